// Round 1
// baseline (3613.474 us; speedup 1.0000x reference)
//
#include <hip/hip_runtime.h>
#include <hip/hip_bf16.h>
#include <math.h>

// Problem constants (B=2, T=2048, C=2048, NH=16, NKV=4, D=128, HALF=64)
#define BB 2
#define TT 2048
#define CC 2048
#define NH 16
#define NKV 4
#define HD 128
#define HALF 64
#define MTOT (BB*TT)          // 4096 rows

// ---------------------------------------------------------------------------
// fp32 tiled GEMM: C[M,N] = A[M,K] @ B[K,N] (+ bias). Row-major everything.
// 128x128 block tile, 256 threads, 8x8 micro-tile per thread, BK=16.
// ---------------------------------------------------------------------------
#define GBM 128
#define GBN 128
#define GBK 16

__global__ __launch_bounds__(256) void gemm_f32(
    const float* __restrict__ A, const float* __restrict__ B,
    const float* __restrict__ bias, float* __restrict__ C,
    int M, int N, int K) {
  __shared__ __align__(16) float As[GBK][GBM + 4];  // As[k][m]
  __shared__ __align__(16) float Bs[GBK][GBN + 4];  // Bs[k][n]

  const int bm = blockIdx.y * GBM;
  const int bn = blockIdx.x * GBN;
  const int tid = threadIdx.x;
  const int tx = tid & 15;   // 0..15 -> col group
  const int ty = tid >> 4;   // 0..15 -> row group

  float acc[8][8];
#pragma unroll
  for (int i = 0; i < 8; ++i)
#pragma unroll
    for (int j = 0; j < 8; ++j) acc[i][j] = 0.f;

  for (int k0 = 0; k0 < K; k0 += GBK) {
    // Stage A tile (GBM x GBK = 2048 elems, 8 per thread), transposed into As[k][m]
#pragma unroll
    for (int i = 0; i < 8; ++i) {
      int idx = i * 256 + tid;          // 0..2047
      int m = idx >> 4, kk = idx & 15;
      As[kk][m] = A[(size_t)(bm + m) * K + k0 + kk];
    }
    // Stage B tile (GBK x GBN = 2048 elems, 8 per thread)
#pragma unroll
    for (int i = 0; i < 8; ++i) {
      int idx = i * 256 + tid;
      int kk = idx >> 7, n = idx & 127;
      Bs[kk][n] = B[(size_t)(k0 + kk) * N + bn + n];
    }
    __syncthreads();

#pragma unroll
    for (int kk = 0; kk < GBK; ++kk) {
      float4 a0 = *(const float4*)&As[kk][ty * 8];
      float4 a1 = *(const float4*)&As[kk][ty * 8 + 4];
      float4 b0 = *(const float4*)&Bs[kk][tx * 8];
      float4 b1 = *(const float4*)&Bs[kk][tx * 8 + 4];
      float a[8] = {a0.x, a0.y, a0.z, a0.w, a1.x, a1.y, a1.z, a1.w};
      float bb[8] = {b0.x, b0.y, b0.z, b0.w, b1.x, b1.y, b1.z, b1.w};
#pragma unroll
      for (int i = 0; i < 8; ++i)
#pragma unroll
        for (int j = 0; j < 8; ++j) acc[i][j] += a[i] * bb[j];
    }
    __syncthreads();
  }

#pragma unroll
  for (int i = 0; i < 8; ++i) {
    size_t m = (size_t)(bm + ty * 8 + i);
#pragma unroll
    for (int j = 0; j < 8; ++j) {
      int n = bn + tx * 8 + j;
      float v = acc[i][j];
      if (bias) v += bias[n];
      C[m * N + n] = v;
    }
  }
}

// ---------------------------------------------------------------------------
// RMSNorm (per head, D=128) + RoPE for q/k, transpose into head-major layout.
// grid = (B*T, NH + NKV + NKV), block = 128 (one thread per dim element).
//   hh in [0,16): q head  -> q[(b*NH+hh)*T + t][d]
//   hh in [16,20): k head -> k[(b*NKV+(hh-16))*T + t][d]
//   hh in [20,24): v head -> plain transpose
// ---------------------------------------------------------------------------
__global__ __launch_bounds__(128) void qkv_post(
    const float* __restrict__ q_lin, const float* __restrict__ k_lin,
    const float* __restrict__ v_lin, const float* __restrict__ cosp,
    const float* __restrict__ sinp, float* __restrict__ q,
    float* __restrict__ k, float* __restrict__ v) {
  const int bt = blockIdx.x;          // 0..B*T-1
  const int hh = blockIdx.y;          // 0..23
  const int t = bt & (TT - 1);
  const int b = bt >> 11;             // T = 2048 = 2^11
  const int d = threadIdx.x;          // 0..127

  __shared__ float sv[HD];
  __shared__ float red[HD];

  if (hh < NH + NKV) {
    // RMSNorm + RoPE path (q or k)
    float val;
    if (hh < NH) val = q_lin[(size_t)bt * (NH * HD) + hh * HD + d];
    else         val = k_lin[(size_t)bt * (NKV * HD) + (hh - NH) * HD + d];
    sv[d] = val;
    red[d] = val * val;
    __syncthreads();
#pragma unroll
    for (int s = 64; s > 0; s >>= 1) {
      if (d < s) red[d] += red[d + s];
      __syncthreads();
    }
    float rms = rsqrtf(red[0] * (1.f / 128.f) + 1.1920929e-7f);  // fp32 eps
    float out;
    if (d < HALF) {
      out = sv[d] * rms * cosp[t * HALF + d] - sv[d + HALF] * rms * sinp[t * HALF + d];
    } else {
      int f = d - HALF;
      out = sv[f] * rms * sinp[t * HALF + f] + sv[d] * rms * cosp[t * HALF + f];
    }
    if (hh < NH)
      q[(((size_t)b * NH + hh) * TT + t) * HD + d] = out;
    else
      k[(((size_t)b * NKV + (hh - NH)) * TT + t) * HD + d] = out;
  } else {
    int h2 = hh - (NH + NKV);
    v[(((size_t)b * NKV + h2) * TT + t) * HD + d] =
        v_lin[(size_t)bt * (NKV * HD) + h2 * HD + d];
  }
}

// ---------------------------------------------------------------------------
// fp32 flash attention, causal, GQA (head h uses kv head h/4).
// grid = (T/32, B*NH), block = 256. 32x32 score tiles, online softmax.
// Thread (r = tid>>3, cg = tid&7): 4 score cols, 16 output cols (cg*16..+15).
// Q/K/V in (B,H,T,D)/(B,KV,T,D); output O in (B,T,H,D) for the final GEMM.
// ---------------------------------------------------------------------------
__global__ __launch_bounds__(256) void attn_fp32(
    const float* __restrict__ Q, const float* __restrict__ K,
    const float* __restrict__ V, float* __restrict__ O) {
  const int qb = blockIdx.x;
  const int bh = blockIdx.y;
  const int b = bh >> 4;
  const int h = bh & 15;
  const int kvh = h >> 2;

  const float* Qp = Q + ((size_t)bh * TT + (size_t)qb * 32) * HD;
  const float* Kp = K + (size_t)(b * NKV + kvh) * TT * HD;
  const float* Vp = V + (size_t)(b * NKV + kvh) * TT * HD;

  __shared__ __align__(16) float Qs[32][132];
  __shared__ __align__(16) float Ks[32][132];
  __shared__ __align__(16) float Vs[32][132];
  __shared__ float Ss[32][33];

  const int tid = threadIdx.x;
  const int r = tid >> 3;
  const int cg = tid & 7;
  const int c0 = cg * 16;

  // Stage Q tile (32x128)
#pragma unroll
  for (int i = 0; i < 16; ++i) {
    int idx = i * 256 + tid;
    Qs[idx >> 7][idx & 127] = Qp[(size_t)(idx >> 7) * HD + (idx & 127)];
  }

  float acc[16];
#pragma unroll
  for (int j = 0; j < 16; ++j) acc[j] = 0.f;
  float m_run = -INFINITY, l_run = 0.f;

  const float scale = 0.08838834764831845f;  // 1/sqrt(128)
  const int q_glob = qb * 32 + r;
  const int ntiles = qb + 1;

  for (int nt = 0; nt < ntiles; ++nt) {
    const int n0 = nt * 32;
    __syncthreads();  // previous iteration's Vs/Ss reads done (also covers Qs staging)
#pragma unroll
    for (int i = 0; i < 16; ++i) {
      int idx = i * 256 + tid;
      int rr = idx >> 7, cc = idx & 127;
      Ks[rr][cc] = Kp[(size_t)(n0 + rr) * HD + cc];
      Vs[rr][cc] = Vp[(size_t)(n0 + rr) * HD + cc];
    }
    __syncthreads();

    // Scores: 4 columns per thread, dot over D=128 via float4 LDS reads
    float s0 = 0.f, s1 = 0.f, s2 = 0.f, s3 = 0.f;
    const float4* q4 = (const float4*)&Qs[r][0];
    const float4* k40 = (const float4*)&Ks[cg * 4 + 0][0];
    const float4* k41 = (const float4*)&Ks[cg * 4 + 1][0];
    const float4* k42 = (const float4*)&Ks[cg * 4 + 2][0];
    const float4* k43 = (const float4*)&Ks[cg * 4 + 3][0];
#pragma unroll 8
    for (int d4 = 0; d4 < 32; ++d4) {
      float4 qv = q4[d4];
      float4 k0 = k40[d4], k1 = k41[d4], k2 = k42[d4], k3 = k43[d4];
      s0 += qv.x * k0.x + qv.y * k0.y + qv.z * k0.z + qv.w * k0.w;
      s1 += qv.x * k1.x + qv.y * k1.y + qv.z * k1.z + qv.w * k1.w;
      s2 += qv.x * k2.x + qv.y * k2.y + qv.z * k2.z + qv.w * k2.w;
      s3 += qv.x * k3.x + qv.y * k3.y + qv.z * k3.z + qv.w * k3.w;
    }
    float svec[4] = {s0 * scale, s1 * scale, s2 * scale, s3 * scale};
#pragma unroll
    for (int jj = 0; jj < 4; ++jj)
      if (n0 + cg * 4 + jj > q_glob) svec[jj] = -INFINITY;

    // Row stats across the 8 lanes owning this row (same wave -> shuffles)
    float lmax = fmaxf(fmaxf(svec[0], svec[1]), fmaxf(svec[2], svec[3]));
#pragma unroll
    for (int off = 1; off < 8; off <<= 1)
      lmax = fmaxf(lmax, __shfl_xor(lmax, off, 64));
    float m_new = fmaxf(m_run, lmax);            // always finite (diagonal present)
    float alpha = __expf(m_run - m_new);         // m_run=-inf -> 0
    float p[4], lsum = 0.f;
#pragma unroll
    for (int jj = 0; jj < 4; ++jj) {
      p[jj] = __expf(svec[jj] - m_new);          // masked -> exp(-inf)=0
      lsum += p[jj];
    }
#pragma unroll
    for (int off = 1; off < 8; off <<= 1) lsum += __shfl_xor(lsum, off, 64);
    l_run = alpha * l_run + lsum;
    m_run = m_new;

#pragma unroll
    for (int jj = 0; jj < 4; ++jj) Ss[r][cg * 4 + jj] = p[jj];
    __syncthreads();  // publish P tile

    // O update: acc = alpha*acc + P @ V_tile
#pragma unroll
    for (int j = 0; j < 16; ++j) acc[j] *= alpha;
    for (int kk = 0; kk < 32; ++kk) {
      float pp = Ss[r][kk];
      const float4* vr = (const float4*)&Vs[kk][c0];
      float4 v0 = vr[0], v1 = vr[1], v2 = vr[2], v3 = vr[3];
      acc[0] += pp * v0.x;  acc[1] += pp * v0.y;
      acc[2] += pp * v0.z;  acc[3] += pp * v0.w;
      acc[4] += pp * v1.x;  acc[5] += pp * v1.y;
      acc[6] += pp * v1.z;  acc[7] += pp * v1.w;
      acc[8] += pp * v2.x;  acc[9] += pp * v2.y;
      acc[10] += pp * v2.z; acc[11] += pp * v2.w;
      acc[12] += pp * v3.x; acc[13] += pp * v3.y;
      acc[14] += pp * v3.z; acc[15] += pp * v3.w;
    }
  }

  // Write O in (B, T, H, D) layout
  float linv = 1.f / l_run;
  float* Op = O + (((size_t)b * TT + q_glob) * NH + h) * HD + c0;
#pragma unroll
  for (int j = 0; j < 16; ++j) Op[j] = acc[j] * linv;
}

// ---------------------------------------------------------------------------
// kernel_launch
// ws layout (floats): q_lin[8M] | k_lin[2M] | v_lin[2M] | q[8M] | k[2M] | v[2M]
// y (attn out, (B,T,H,D)) aliases q_lin (dead after qkv_post). ~100.7 MB total.
// ---------------------------------------------------------------------------
extern "C" void kernel_launch(void* const* d_in, const int* in_sizes, int n_in,
                              void* d_out, int out_size, void* d_ws, size_t ws_size,
                              hipStream_t stream) {
  (void)in_sizes; (void)n_in; (void)out_size; (void)ws_size;
  const float* x    = (const float*)d_in[0];
  const float* cosp = (const float*)d_in[1];
  const float* sinp = (const float*)d_in[2];
  const float* Wq   = (const float*)d_in[3];
  const float* Wk   = (const float*)d_in[4];
  const float* Wv   = (const float*)d_in[5];
  const float* Wo   = (const float*)d_in[6];
  const float* bo   = (const float*)d_in[7];
  float* out = (float*)d_out;
  float* ws  = (float*)d_ws;

  float* q_lin = ws;                                   // 8388608
  float* k_lin = q_lin + (size_t)MTOT * CC;            // 2097152
  float* v_lin = k_lin + (size_t)MTOT * NKV * HD;      // 2097152
  float* q     = v_lin + (size_t)MTOT * NKV * HD;      // 8388608
  float* k     = q + (size_t)MTOT * CC;                // 2097152
  float* v     = k + (size_t)MTOT * NKV * HD;          // 2097152
  float* y     = q_lin;                                // alias (q_lin dead)

  // QKV projections
  gemm_f32<<<dim3(CC / GBN, MTOT / GBM), 256, 0, stream>>>(x, Wq, nullptr, q_lin, MTOT, CC, CC);
  gemm_f32<<<dim3((NKV * HD) / GBN, MTOT / GBM), 256, 0, stream>>>(x, Wk, nullptr, k_lin, MTOT, NKV * HD, CC);
  gemm_f32<<<dim3((NKV * HD) / GBN, MTOT / GBM), 256, 0, stream>>>(x, Wv, nullptr, v_lin, MTOT, NKV * HD, CC);

  // RMSNorm + RoPE + transpose
  qkv_post<<<dim3(MTOT, NH + 2 * NKV), 128, 0, stream>>>(q_lin, k_lin, v_lin, cosp, sinp, q, k, v);

  // Causal flash attention
  attn_fp32<<<dim3(TT / 32, BB * NH), 256, 0, stream>>>(q, k, v, y);

  // Output projection + bias
  gemm_f32<<<dim3(CC / GBN, MTOT / GBM), 256, 0, stream>>>(y, Wo, bo, out, MTOT, CC, CC);
}

// Round 2
// 474.118 us; speedup vs baseline: 7.6215x; 7.6215x over previous
//
#include <hip/hip_runtime.h>
#include <hip/hip_bf16.h>
#include <math.h>

// Problem constants (B=2, T=2048, C=2048, NH=16, NKV=4, D=128, HALF=64)
#define BB 2
#define TT 2048
#define CC 2048
#define NH 16
#define NKV 4
#define HD 128
#define HALF 64
#define MTOT (BB*TT)            // 4096
#define NQKV (CC + 2*NKV*HD)    // 3072 (fused q|k|v columns)

typedef unsigned short u16;
typedef __attribute__((ext_vector_type(8))) short bf16x8;
typedef __attribute__((ext_vector_type(4))) float f32x4;

// fp32 -> bf16 (round-to-nearest-even), header-independent
__device__ __forceinline__ u16 f2bf(float f) {
  unsigned u = __float_as_uint(f);
  unsigned r = (u + 0x7FFFu + ((u >> 16) & 1u)) >> 16;
  return (u16)r;
}

// async global->LDS, 16B per lane. lds ptr must be wave-uniform.
__device__ __forceinline__ void gl_lds16(const void* g, void* l) {
  __builtin_amdgcn_global_load_lds(
      (const __attribute__((address_space(1))) unsigned int*)g,
      (__attribute__((address_space(3))) unsigned int*)l, 16, 0, 0);
}

// ---------------------------------------------------------------------------
// x (fp32) -> bf16, 8 elems/thread
// ---------------------------------------------------------------------------
__global__ __launch_bounds__(256) void convert_bf16(
    const float* __restrict__ src, u16* __restrict__ dst, int n8) {
  int i = blockIdx.x * 256 + threadIdx.x;
  if (i >= n8) return;
  const float4* s4 = (const float4*)src;
  float4 a = s4[(size_t)i * 2], b = s4[(size_t)i * 2 + 1];
  bf16x8 o;
  o[0] = (short)f2bf(a.x); o[1] = (short)f2bf(a.y);
  o[2] = (short)f2bf(a.z); o[3] = (short)f2bf(a.w);
  o[4] = (short)f2bf(b.x); o[5] = (short)f2bf(b.y);
  o[6] = (short)f2bf(b.z); o[7] = (short)f2bf(b.w);
  ((bf16x8*)dst)[i] = o;
}

// ---------------------------------------------------------------------------
// W (K=2048 rows, N cols, fp32) -> Wt[(row_off+n)*2048 + k] bf16 (transposed)
// grid (N/32, 64), block (32,8)
// ---------------------------------------------------------------------------
__global__ __launch_bounds__(256) void transpose_w(
    const float* __restrict__ W, u16* __restrict__ Wt, int N, int row_off) {
  __shared__ float tile[32][33];
  const int n0 = blockIdx.x * 32, k0 = blockIdx.y * 32;
  const int tx = threadIdx.x, ty = threadIdx.y;
#pragma unroll
  for (int i = 0; i < 4; ++i)
    tile[ty + 8 * i][tx] = W[(size_t)(k0 + ty + 8 * i) * N + n0 + tx];
  __syncthreads();
#pragma unroll
  for (int i = 0; i < 4; ++i)
    Wt[(size_t)(row_off + n0 + ty + 8 * i) * CC + k0 + tx] =
        f2bf(tile[tx][ty + 8 * i]);
}

// ---------------------------------------------------------------------------
// v part of qkv_lin (fp32, col 2560+kv*128+d) -> vt (B,KV,D,T) bf16
// grid (T/32, D/32, B*NKV), block (32,8)
// ---------------------------------------------------------------------------
__global__ __launch_bounds__(256) void v_transpose(
    const float* __restrict__ qkv_lin, u16* __restrict__ vt) {
  __shared__ float tile[32][33];
  const int t0 = blockIdx.x * 32, d0 = blockIdx.y * 32;
  const int p = blockIdx.z;             // b*NKV + kv
  const int b = p >> 2, kv = p & 3;
  const int tx = threadIdx.x, ty = threadIdx.y;
#pragma unroll
  for (int i = 0; i < 4; ++i)
    tile[ty + 8 * i][tx] =
        qkv_lin[(size_t)(b * TT + t0 + ty + 8 * i) * NQKV + CC + NKV * HD + kv * HD + d0 + tx];
  __syncthreads();
#pragma unroll
  for (int i = 0; i < 4; ++i)
    vt[((size_t)p * HD + d0 + ty + 8 * i) * TT + t0 + tx] =
        f2bf(tile[tx][ty + 8 * i]);
}

// ---------------------------------------------------------------------------
// bf16 MFMA GEMM (m97 structure): C[M,N] fp32 = A[M,K]bf16 @ Bt[N,K]bf16^T
// 128x128 tile, BK=32, 256 thr (4 waves), wave tile 64x64 (4x4 of 16x16x32).
// global_load_lds width-16 staging, no pad (contiguous constraint).
// ---------------------------------------------------------------------------
__global__ __launch_bounds__(256) void gemm_bt_bf16(
    const u16* __restrict__ A, const u16* __restrict__ Bt,
    const float* __restrict__ bias, float* __restrict__ C,
    int M, int N, int K) {
  __shared__ u16 As[128 * 32];
  __shared__ u16 Bs[128 * 32];
  const int tid = threadIdx.x;
  const int wave = tid >> 6, lane = tid & 63;
  const int quad = lane >> 4, lo = lane & 15;
  const int bm = blockIdx.y * 128, bn = blockIdx.x * 128;
  const int wm = (wave & 1) * 64, wn = (wave >> 1) * 64;

  f32x4 acc[4][4];
#pragma unroll
  for (int i = 0; i < 4; ++i)
#pragma unroll
    for (int j = 0; j < 4; ++j)
#pragma unroll
      for (int r = 0; r < 4; ++r) acc[i][j][r] = 0.f;

  const int iss0 = wave * 2, iss1 = wave * 2 + 1;
  const int e0 = iss0 * 512 + lane * 8, e1 = iss1 * 512 + lane * 8;
  const int r0 = e0 >> 5, c0 = e0 & 31;
  const int r1 = e1 >> 5, c1 = e1 & 31;

  for (int k0 = 0; k0 < K; k0 += 32) {
    gl_lds16(A + (size_t)(bm + r0) * K + k0 + c0, (char*)As + iss0 * 1024);
    gl_lds16(A + (size_t)(bm + r1) * K + k0 + c1, (char*)As + iss1 * 1024);
    gl_lds16(Bt + (size_t)(bn + r0) * K + k0 + c0, (char*)Bs + iss0 * 1024);
    gl_lds16(Bt + (size_t)(bn + r1) * K + k0 + c1, (char*)Bs + iss1 * 1024);
    __syncthreads();

    bf16x8 af[4], bg[4];
#pragma unroll
    for (int i = 0; i < 4; ++i)
      af[i] = *(const bf16x8*)&As[(wm + i * 16 + lo) * 32 + quad * 8];
#pragma unroll
    for (int j = 0; j < 4; ++j)
      bg[j] = *(const bf16x8*)&Bs[(wn + j * 16 + lo) * 32 + quad * 8];
#pragma unroll
    for (int i = 0; i < 4; ++i)
#pragma unroll
      for (int j = 0; j < 4; ++j)
        acc[i][j] = __builtin_amdgcn_mfma_f32_16x16x32_bf16(af[i], bg[j], acc[i][j], 0, 0, 0);
    __syncthreads();
  }

#pragma unroll
  for (int i = 0; i < 4; ++i)
#pragma unroll
    for (int j = 0; j < 4; ++j)
#pragma unroll
      for (int r = 0; r < 4; ++r) {
        int row = bm + wm + i * 16 + quad * 4 + r;
        int col = bn + wn + j * 16 + lo;
        float v = acc[i][j][r];
        if (bias) v += bias[col];
        C[(size_t)row * N + col] = v;
      }
}

// ---------------------------------------------------------------------------
// RMSNorm (per head) + RoPE on q/k from fused qkv_lin; writes bf16 head-major.
// grid (B*T, NH+NKV), block 128
// ---------------------------------------------------------------------------
__global__ __launch_bounds__(128) void qkv_post(
    const float* __restrict__ qkv_lin, const float* __restrict__ cosp,
    const float* __restrict__ sinp, u16* __restrict__ q, u16* __restrict__ k) {
  const int bt = blockIdx.x, hh = blockIdx.y;
  const int t = bt & (TT - 1), b = bt >> 11;
  const int d = threadIdx.x;

  __shared__ float sv[HD];
  __shared__ float red[HD];

  int col = (hh < NH) ? hh * HD + d : CC + (hh - NH) * HD + d;
  float val = qkv_lin[(size_t)bt * NQKV + col];
  sv[d] = val;
  red[d] = val * val;
  __syncthreads();
#pragma unroll
  for (int s = 64; s > 0; s >>= 1) {
    if (d < s) red[d] += red[d + s];
    __syncthreads();
  }
  float rms = rsqrtf(red[0] * (1.f / 128.f) + 1.1920929e-7f);
  float out;
  if (d < HALF) {
    out = sv[d] * rms * cosp[t * HALF + d] - sv[d + HALF] * rms * sinp[t * HALF + d];
  } else {
    int f = d - HALF;
    out = sv[f] * rms * sinp[t * HALF + f] + sv[d] * rms * cosp[t * HALF + f];
  }
  if (hh < NH)
    q[(((size_t)(b * NH + hh)) * TT + t) * HD + d] = f2bf(out);
  else
    k[(((size_t)(b * NKV + (hh - NH))) * TT + t) * HD + d] = f2bf(out);
}

// ---------------------------------------------------------------------------
// MFMA flash attention, causal, GQA. grid (T/64, B*NH), block 256 (4 waves).
// Block: 64 q rows (16/wave); KV tiles of 64. Q,K (B,H|KV,T,D); V (B,KV,D,T).
// Output Y bf16 in (B*T, C) layout (A operand of out-proj GEMM).
// ---------------------------------------------------------------------------
__global__ __launch_bounds__(256) void attn_mfma(
    const u16* __restrict__ Qb, const u16* __restrict__ Kb,
    const u16* __restrict__ Vt, u16* __restrict__ Y) {
  const int qb = gridDim.x - 1 - blockIdx.x;   // heavy blocks first
  const int bh = blockIdx.y;
  const int b = bh >> 4, h = bh & 15, kvh = h >> 2;
  const int tid = threadIdx.x;
  const int wave = tid >> 6, lane = tid & 63;
  const int quad = lane >> 4, lo = lane & 15;

  __shared__ u16 Ks[64 * 136];   // [kv][d], pad 8
  __shared__ u16 Vs[128 * 72];   // [d][kv], pad 8
  __shared__ u16 Ps[4 * 16 * 72];

  const u16* Qg = Qb + ((size_t)(b * NH + h) * TT + qb * 64) * HD;
  const u16* Kg = Kb + (size_t)(b * NKV + kvh) * TT * HD;
  const u16* Vg = Vt + (size_t)(b * NKV + kvh) * HD * TT;

  // Q fragments (A-op), 16 rows per wave, preloaded from global
  bf16x8 aq[4];
  const int qrow = wave * 16 + lo;
#pragma unroll
  for (int kc = 0; kc < 4; ++kc)
    aq[kc] = *(const bf16x8*)(Qg + (size_t)qrow * HD + kc * 32 + quad * 8);

  f32x4 oacc[8];
#pragma unroll
  for (int i = 0; i < 8; ++i)
#pragma unroll
    for (int r = 0; r < 4; ++r) oacc[i][r] = 0.f;
  float m_run[4] = {-INFINITY, -INFINITY, -INFINITY, -INFINITY};
  float l_run[4] = {0.f, 0.f, 0.f, 0.f};
  const float scale = 0.08838834764831845f;    // 1/sqrt(128)
  const int q_glob_base = qb * 64 + wave * 16 + quad * 4;
  u16* Pw = Ps + wave * 16 * 72;

  for (int nt = 0; nt <= qb; ++nt) {
    const int t0 = nt * 64;
    __syncthreads();  // prior iteration's Ks/Vs/Ps reads complete
#pragma unroll
    for (int i = 0; i < 4; ++i) {
      int c = i * 256 + tid;                   // 1024 chunks of 8 bf16
      int kr = c >> 4, kc8 = c & 15;
      *(bf16x8*)&Ks[kr * 136 + kc8 * 8] =
          *(const bf16x8*)(Kg + (size_t)(t0 + kr) * HD + kc8 * 8);
      int vd = c >> 3, vc8 = c & 7;
      *(bf16x8*)&Vs[vd * 72 + vc8 * 8] =
          *(const bf16x8*)(Vg + (size_t)vd * TT + t0 + vc8 * 8);
    }
    __syncthreads();

    // S = Q K^T (16x64 per wave)
    f32x4 sacc[4];
#pragma unroll
    for (int ct = 0; ct < 4; ++ct)
#pragma unroll
      for (int r = 0; r < 4; ++r) sacc[ct][r] = 0.f;
#pragma unroll
    for (int ct = 0; ct < 4; ++ct)
#pragma unroll
      for (int kc = 0; kc < 4; ++kc) {
        bf16x8 bk = *(const bf16x8*)&Ks[(ct * 16 + lo) * 136 + kc * 32 + quad * 8];
        sacc[ct] = __builtin_amdgcn_mfma_f32_16x16x32_bf16(aq[kc], bk, sacc[ct], 0, 0, 0);
      }

    // online softmax
    float p[4][4];
    if (nt == qb) {
#pragma unroll
      for (int ct = 0; ct < 4; ++ct) {
        int kcol = t0 + ct * 16 + lo;
#pragma unroll
        for (int r = 0; r < 4; ++r) {
          float s = sacc[ct][r] * scale;
          p[ct][r] = (kcol > q_glob_base + r) ? -INFINITY : s;
        }
      }
    } else {
#pragma unroll
      for (int ct = 0; ct < 4; ++ct)
#pragma unroll
        for (int r = 0; r < 4; ++r) p[ct][r] = sacc[ct][r] * scale;
    }
    float rowmax[4];
#pragma unroll
    for (int r = 0; r < 4; ++r)
      rowmax[r] = fmaxf(fmaxf(p[0][r], p[1][r]), fmaxf(p[2][r], p[3][r]));
#pragma unroll
    for (int m = 1; m < 16; m <<= 1)
#pragma unroll
      for (int r = 0; r < 4; ++r)
        rowmax[r] = fmaxf(rowmax[r], __shfl_xor(rowmax[r], m, 64));
    float alpha[4], lsum[4];
#pragma unroll
    for (int r = 0; r < 4; ++r) {
      float mn = fmaxf(m_run[r], rowmax[r]);
      alpha[r] = __expf(m_run[r] - mn);
      m_run[r] = mn;
      float ls = 0.f;
#pragma unroll
      for (int ct = 0; ct < 4; ++ct) {
        p[ct][r] = __expf(p[ct][r] - mn);
        ls += p[ct][r];
      }
      lsum[r] = ls;
    }
#pragma unroll
    for (int m = 1; m < 16; m <<= 1)
#pragma unroll
      for (int r = 0; r < 4; ++r) lsum[r] += __shfl_xor(lsum[r], m, 64);
#pragma unroll
    for (int r = 0; r < 4; ++r) l_run[r] = alpha[r] * l_run[r] + lsum[r];

    // P -> LDS (C/D layout -> A-op layout round trip), bf16
#pragma unroll
    for (int ct = 0; ct < 4; ++ct)
#pragma unroll
      for (int r = 0; r < 4; ++r)
        Pw[(quad * 4 + r) * 72 + ct * 16 + lo] = f2bf(p[ct][r]);
    __syncthreads();  // publish P (and order vs reads)

    // O = alpha*O + P @ V
#pragma unroll
    for (int dt = 0; dt < 8; ++dt)
#pragma unroll
      for (int r = 0; r < 4; ++r) oacc[dt][r] *= alpha[r];
#pragma unroll
    for (int kc2 = 0; kc2 < 2; ++kc2) {
      bf16x8 ap = *(const bf16x8*)&Pw[lo * 72 + kc2 * 32 + quad * 8];
#pragma unroll
      for (int dt = 0; dt < 8; ++dt) {
        bf16x8 bv = *(const bf16x8*)&Vs[(dt * 16 + lo) * 72 + kc2 * 32 + quad * 8];
        oacc[dt] = __builtin_amdgcn_mfma_f32_16x16x32_bf16(ap, bv, oacc[dt], 0, 0, 0);
      }
    }
  }

  // epilogue: Y[(b*T + trow) * C + h*128 + d] bf16
  float inv[4];
#pragma unroll
  for (int r = 0; r < 4; ++r) inv[r] = 1.f / l_run[r];
  const size_t mbase = (size_t)(b * TT + qb * 64 + wave * 16 + quad * 4);
#pragma unroll
  for (int dt = 0; dt < 8; ++dt)
#pragma unroll
    for (int r = 0; r < 4; ++r)
      Y[(mbase + r) * CC + h * HD + dt * 16 + lo] = f2bf(oacc[dt][r] * inv[r]);
}

// ---------------------------------------------------------------------------
// kernel_launch. ws layout (bytes):
//   [0,16M):   xb (bf16 x)        -> later qb_buf (bf16 q, B,H,T,D)
//   [16M,28M): Wt (bf16 qkv^T)    -> later kb (4M) + vt (8M)
//   [28M,76M): qkv_lin fp32       -> first 16M later y (bf16, M x C)
//   [76M,84M): Wot (bf16 Wo^T)
// ---------------------------------------------------------------------------
extern "C" void kernel_launch(void* const* d_in, const int* in_sizes, int n_in,
                              void* d_out, int out_size, void* d_ws, size_t ws_size,
                              hipStream_t stream) {
  (void)in_sizes; (void)n_in; (void)out_size; (void)ws_size;
  const float* x    = (const float*)d_in[0];
  const float* cosp = (const float*)d_in[1];
  const float* sinp = (const float*)d_in[2];
  const float* Wq   = (const float*)d_in[3];
  const float* Wk   = (const float*)d_in[4];
  const float* Wv   = (const float*)d_in[5];
  const float* Wo   = (const float*)d_in[6];
  const float* bo   = (const float*)d_in[7];
  float* out = (float*)d_out;
  char* ws = (char*)d_ws;

  const size_t MB = 1024 * 1024;
  u16*   xb      = (u16*)(ws);
  u16*   Wt      = (u16*)(ws + 16 * MB);
  float* qkv_lin = (float*)(ws + 28 * MB);
  u16*   Wot     = (u16*)(ws + 76 * MB);
  u16*   qb_buf  = (u16*)(ws);             // alias xb (dead after GEMM1)
  u16*   kb      = (u16*)(ws + 16 * MB);   // alias Wt
  u16*   vt      = (u16*)(ws + 20 * MB);   // alias Wt+4M
  u16*   y       = (u16*)(ws + 28 * MB);   // alias qkv_lin head

  // 1. x -> bf16
  convert_bf16<<<(MTOT * CC / 8 + 255) / 256, 256, 0, stream>>>(x, xb, MTOT * CC / 8);

  // 2. weight transposes -> bf16 (fused qkv: rows 0..2047 Wq, 2048.. Wk, 2560.. Wv)
  transpose_w<<<dim3(CC / 32, CC / 32), dim3(32, 8), 0, stream>>>(Wq, Wt, CC, 0);
  transpose_w<<<dim3(NKV * HD / 32, CC / 32), dim3(32, 8), 0, stream>>>(Wk, Wt, NKV * HD, CC);
  transpose_w<<<dim3(NKV * HD / 32, CC / 32), dim3(32, 8), 0, stream>>>(Wv, Wt, NKV * HD, CC + NKV * HD);
  transpose_w<<<dim3(CC / 32, CC / 32), dim3(32, 8), 0, stream>>>(Wo, Wot, CC, 0);

  // 3. fused QKV GEMM: (M=4096, N=3072, K=2048) fp32 out
  gemm_bt_bf16<<<dim3(NQKV / 128, MTOT / 128), 256, 0, stream>>>(
      xb, Wt, nullptr, qkv_lin, MTOT, NQKV, CC);

  // 4. RMSNorm + RoPE -> bf16 q/k head-major
  qkv_post<<<dim3(MTOT, NH + NKV), 128, 0, stream>>>(qkv_lin, cosp, sinp, qb_buf, kb);

  // 5. V -> (B,KV,D,T) bf16
  v_transpose<<<dim3(TT / 32, HD / 32, BB * NKV), dim3(32, 8), 0, stream>>>(qkv_lin, vt);

  // 6. MFMA flash attention -> y bf16 (M x C)
  attn_mfma<<<dim3(TT / 64, BB * NH), 256, 0, stream>>>(qb_buf, kb, vt, y);

  // 7. out-proj GEMM + bias: (M=4096, N=2048, K=2048) fp32 out
  gemm_bt_bf16<<<dim3(CC / 128, MTOT / 128), 256, 0, stream>>>(
      y, Wot, bo, out, MTOT, CC, CC);
}

// Round 3
// 409.955 us; speedup vs baseline: 8.8143x; 1.1565x over previous
//
#include <hip/hip_runtime.h>
#include <hip/hip_bf16.h>
#include <math.h>

// Problem constants (B=2, T=2048, C=2048, NH=16, NKV=4, D=128, HALF=64)
#define BB 2
#define TT 2048
#define CC 2048
#define NH 16
#define NKV 4
#define HD 128
#define HALF 64
#define MTOT (BB*TT)            // 4096
#define NQKV (CC + 2*NKV*HD)    // 3072 (fused q|k|v columns)

typedef unsigned short u16;
typedef __attribute__((ext_vector_type(8))) short bf16x8;
typedef __attribute__((ext_vector_type(4))) float f32x4;

// fp32 -> bf16 (round-to-nearest-even)
__device__ __forceinline__ u16 f2bf(float f) {
  unsigned u = __float_as_uint(f);
  unsigned r = (u + 0x7FFFu + ((u >> 16) & 1u)) >> 16;
  return (u16)r;
}

// async global->LDS, 16B per lane; lds base must be wave-uniform (HW adds lane*16)
__device__ __forceinline__ void gl_lds16(const void* g, void* l) {
  __builtin_amdgcn_global_load_lds(
      (const __attribute__((address_space(1))) unsigned int*)g,
      (__attribute__((address_space(3))) unsigned int*)l, 16, 0, 0);
}

// ---------------------------------------------------------------------------
// x (fp32) -> bf16, 8 elems/thread
// ---------------------------------------------------------------------------
__global__ __launch_bounds__(256) void convert_bf16(
    const float* __restrict__ src, u16* __restrict__ dst, int n8) {
  int i = blockIdx.x * 256 + threadIdx.x;
  if (i >= n8) return;
  const float4* s4 = (const float4*)src;
  float4 a = s4[(size_t)i * 2], b = s4[(size_t)i * 2 + 1];
  bf16x8 o;
  o[0] = (short)f2bf(a.x); o[1] = (short)f2bf(a.y);
  o[2] = (short)f2bf(a.z); o[3] = (short)f2bf(a.w);
  o[4] = (short)f2bf(b.x); o[5] = (short)f2bf(b.y);
  o[6] = (short)f2bf(b.z); o[7] = (short)f2bf(b.w);
  ((bf16x8*)dst)[i] = o;
}

// ---------------------------------------------------------------------------
// W (K=2048 rows, N cols, fp32) -> Wt[(row_off+n)*2048 + k] bf16 (transposed)
// ---------------------------------------------------------------------------
__global__ __launch_bounds__(256) void transpose_w(
    const float* __restrict__ W, u16* __restrict__ Wt, int N, int row_off) {
  __shared__ float tile[32][33];
  const int n0 = blockIdx.x * 32, k0 = blockIdx.y * 32;
  const int tx = threadIdx.x, ty = threadIdx.y;
#pragma unroll
  for (int i = 0; i < 4; ++i)
    tile[ty + 8 * i][tx] = W[(size_t)(k0 + ty + 8 * i) * N + n0 + tx];
  __syncthreads();
#pragma unroll
  for (int i = 0; i < 4; ++i)
    Wt[(size_t)(row_off + n0 + ty + 8 * i) * CC + k0 + tx] =
        f2bf(tile[tx][ty + 8 * i]);
}

// ---------------------------------------------------------------------------
// v part of qkv_lin (fp32) -> vt (B,KV,D,T) bf16
// ---------------------------------------------------------------------------
__global__ __launch_bounds__(256) void v_transpose(
    const float* __restrict__ qkv_lin, u16* __restrict__ vt) {
  __shared__ float tile[32][33];
  const int t0 = blockIdx.x * 32, d0 = blockIdx.y * 32;
  const int p = blockIdx.z;             // b*NKV + kv
  const int b = p >> 2, kv = p & 3;
  const int tx = threadIdx.x, ty = threadIdx.y;
#pragma unroll
  for (int i = 0; i < 4; ++i)
    tile[ty + 8 * i][tx] =
        qkv_lin[(size_t)(b * TT + t0 + ty + 8 * i) * NQKV + CC + NKV * HD + kv * HD + d0 + tx];
  __syncthreads();
#pragma unroll
  for (int i = 0; i < 4; ++i)
    vt[((size_t)p * HD + d0 + ty + 8 * i) * TT + t0 + tx] =
        f2bf(tile[tx][ty + 8 * i]);
}

// ---------------------------------------------------------------------------
// bf16 MFMA GEMM (m97 structure), unchanged from round 2 (known good).
// ---------------------------------------------------------------------------
__global__ __launch_bounds__(256) void gemm_bt_bf16(
    const u16* __restrict__ A, const u16* __restrict__ Bt,
    const float* __restrict__ bias, float* __restrict__ C,
    int M, int N, int K) {
  __shared__ u16 As[128 * 32];
  __shared__ u16 Bs[128 * 32];
  const int tid = threadIdx.x;
  const int wave = tid >> 6, lane = tid & 63;
  const int quad = lane >> 4, lo = lane & 15;
  const int bm = blockIdx.y * 128, bn = blockIdx.x * 128;
  const int wm = (wave & 1) * 64, wn = (wave >> 1) * 64;

  f32x4 acc[4][4];
#pragma unroll
  for (int i = 0; i < 4; ++i)
#pragma unroll
    for (int j = 0; j < 4; ++j)
#pragma unroll
      for (int r = 0; r < 4; ++r) acc[i][j][r] = 0.f;

  const int iss0 = wave * 2, iss1 = wave * 2 + 1;
  const int e0 = iss0 * 512 + lane * 8, e1 = iss1 * 512 + lane * 8;
  const int r0 = e0 >> 5, c0 = e0 & 31;
  const int r1 = e1 >> 5, c1 = e1 & 31;

  for (int k0 = 0; k0 < K; k0 += 32) {
    gl_lds16(A + (size_t)(bm + r0) * K + k0 + c0, (char*)As + iss0 * 1024);
    gl_lds16(A + (size_t)(bm + r1) * K + k0 + c1, (char*)As + iss1 * 1024);
    gl_lds16(Bt + (size_t)(bn + r0) * K + k0 + c0, (char*)Bs + iss0 * 1024);
    gl_lds16(Bt + (size_t)(bn + r1) * K + k0 + c1, (char*)Bs + iss1 * 1024);
    __syncthreads();

    bf16x8 af[4], bg[4];
#pragma unroll
    for (int i = 0; i < 4; ++i)
      af[i] = *(const bf16x8*)&As[(wm + i * 16 + lo) * 32 + quad * 8];
#pragma unroll
    for (int j = 0; j < 4; ++j)
      bg[j] = *(const bf16x8*)&Bs[(wn + j * 16 + lo) * 32 + quad * 8];
#pragma unroll
    for (int i = 0; i < 4; ++i)
#pragma unroll
      for (int j = 0; j < 4; ++j)
        acc[i][j] = __builtin_amdgcn_mfma_f32_16x16x32_bf16(af[i], bg[j], acc[i][j], 0, 0, 0);
    __syncthreads();
  }

#pragma unroll
  for (int i = 0; i < 4; ++i)
#pragma unroll
    for (int j = 0; j < 4; ++j)
#pragma unroll
      for (int r = 0; r < 4; ++r) {
        int row = bm + wm + i * 16 + quad * 4 + r;
        int col = bn + wn + j * 16 + lo;
        float v = acc[i][j][r];
        if (bias) v += bias[col];
        C[(size_t)row * N + col] = v;
      }
}

// ---------------------------------------------------------------------------
// RMSNorm + RoPE, one wave per (b,t,head). grid (B*T, 5), block 256 (4 waves).
// Lane owns dims (lane, lane+64) — the natural RoPE pair.
// ---------------------------------------------------------------------------
__global__ __launch_bounds__(256) void qkv_post(
    const float* __restrict__ qkv_lin, const float* __restrict__ cosp,
    const float* __restrict__ sinp, u16* __restrict__ q, u16* __restrict__ k) {
  const int bt = blockIdx.x;
  const int hh = blockIdx.y * 4 + (threadIdx.x >> 6);   // 0..19
  const int lane = threadIdx.x & 63;
  const int t = bt & (TT - 1), b = bt >> 11;
  const int col = (hh < NH) ? hh * HD : CC + (hh - NH) * HD;
  const float* src = qkv_lin + (size_t)bt * NQKV + col;
  float v1 = src[lane], v2 = src[lane + 64];
  float ss = v1 * v1 + v2 * v2;
#pragma unroll
  for (int mm = 1; mm < 64; mm <<= 1) ss += __shfl_xor(ss, mm, 64);
  float rms = rsqrtf(ss * (1.f / 128.f) + 1.1920929e-7f);
  float c = cosp[t * HALF + lane], s = sinp[t * HALF + lane];
  float o1 = v1 * rms * c - v2 * rms * s;
  float o2 = v1 * rms * s + v2 * rms * c;
  if (hh < NH) {
    u16* dst = q + (((size_t)(b * NH + hh)) * TT + t) * HD;
    dst[lane] = f2bf(o1); dst[lane + 64] = f2bf(o2);
  } else {
    u16* dst = k + (((size_t)(b * NKV + (hh - NH))) * TT + t) * HD;
    dst[lane] = f2bf(o1); dst[lane + 64] = f2bf(o2);
  }
}

// ---------------------------------------------------------------------------
// MFMA flash attention v2. grid (16, 32), block 256 (4 waves).
// Block = 128 q rows (32/wave, 2 row-blocks of 16); KV tiles of 64.
// K/V staged via async global_load_lds into FRAGMENT-ORDERED LDS (16B chunk
// per (set,lane)), double-buffered; ONE barrier per KV tile. P tile is
// wave-private (fragment-ordered, no barrier). LDS = 32+32+16 = 80 KB exactly
// -> 2 blocks/CU. Heavy q-tiles launched first (qb = 15 - blockIdx.x).
// ---------------------------------------------------------------------------
__global__ __launch_bounds__(256, 2) void attn_mfma(
    const u16* __restrict__ Qb, const u16* __restrict__ Kb,
    const u16* __restrict__ Vt, u16* __restrict__ Y) {
  __shared__ u16 Ks[2][8192];   // 16 sets (ct*4+kc) x 512 elems, per buf
  __shared__ u16 Vs[2][8192];   // 16 sets (dt*2+kc2) x 512 elems, per buf
  __shared__ u16 Ps[4][2048];   // per wave: 4 sets (rb*2+kc2) x 512 elems

  const int qb = (int)gridDim.x - 1 - blockIdx.x;
  const int bh = blockIdx.y;
  const int b = bh >> 4, h = bh & 15, kvh = h >> 2;
  const int tid = threadIdx.x;
  const int wave = tid >> 6, lane = tid & 63;
  const int quad = lane >> 4, lo = lane & 15;

  const u16* Qg = Qb + ((size_t)(b * NH + h) * TT + qb * 128 + wave * 32) * HD;
  const u16* Kg = Kb + (size_t)(b * NKV + kvh) * TT * HD;
  const u16* Vg = Vt + (size_t)(b * NKV + kvh) * HD * TT;

  // Q fragments: 2 row-blocks x 4 k-chunks (A-op: m=lo, k=quad*8+j)
  bf16x8 aq[2][4];
#pragma unroll
  for (int rb = 0; rb < 2; ++rb)
#pragma unroll
    for (int kc = 0; kc < 4; ++kc)
      aq[rb][kc] = *(const bf16x8*)(Qg + (size_t)(rb * 16 + lo) * HD + kc * 32 + quad * 8);

  // staging pointers: wave stages sets wave*4..wave*4+3 for both K and V
  const u16* kg[4];
  const u16* vg[4];
  u16* kl0[4]; u16* kl1[4]; u16* vl0[4]; u16* vl1[4];
#pragma unroll
  for (int c = 0; c < 4; ++c) {
    const int s = wave * 4 + c;
    const int ct = s >> 2, kq = s & 3;          // K set -> (ct, kc)
    kg[c] = Kg + (size_t)(ct * 16 + lo) * HD + kq * 32 + quad * 8;
    const int dt = s >> 1, k2 = s & 1;          // V set -> (dt, kc2)
    vg[c] = Vg + (size_t)(dt * 16 + lo) * TT + k2 * 32 + quad * 8;
    kl0[c] = &Ks[0][s * 512]; kl1[c] = &Ks[1][s * 512];
    vl0[c] = &Vs[0][s * 512]; vl1[c] = &Vs[1][s * 512];
  }

  f32x4 oacc[2][8];
#pragma unroll
  for (int rb = 0; rb < 2; ++rb)
#pragma unroll
    for (int dt = 0; dt < 8; ++dt)
#pragma unroll
      for (int r = 0; r < 4; ++r) oacc[rb][dt][r] = 0.f;
  float m_run[2][4], l_run[2][4];
#pragma unroll
  for (int rb = 0; rb < 2; ++rb)
#pragma unroll
    for (int r = 0; r < 4; ++r) { m_run[rb][r] = -INFINITY; l_run[rb][r] = 0.f; }

  u16* Pw = Ps[wave];
  const float scale = 0.08838834764831845f;     // 1/sqrt(128)
  const int ntiles = 2 * qb + 2;

  // prologue: stage tile 0 -> buf 0
#pragma unroll
  for (int c = 0; c < 4; ++c) {
    gl_lds16(kg[c], kl0[c]); kg[c] += 64 * HD;
    gl_lds16(vg[c], vl0[c]); vg[c] += 64;
  }

  for (int nt = 0; nt < ntiles; ++nt) {
    const int par = nt & 1;
    __syncthreads();   // drains vmcnt: buf[par] ready; prior readers of buf[par^1] done
    if (nt + 1 < ntiles) {
      if (par == 0) {
#pragma unroll
        for (int c = 0; c < 4; ++c) {
          gl_lds16(kg[c], kl1[c]); kg[c] += 64 * HD;
          gl_lds16(vg[c], vl1[c]); vg[c] += 64;
        }
      } else {
#pragma unroll
        for (int c = 0; c < 4; ++c) {
          gl_lds16(kg[c], kl0[c]); kg[c] += 64 * HD;
          gl_lds16(vg[c], vl0[c]); vg[c] += 64;
        }
      }
    }
    const u16* ksb = Ks[par];
    const u16* vsb = Vs[par];
    const int t0 = nt * 64;

    // S = Q K^T: 32 MFMAs, 16 K-frag reads (reused across both row-blocks)
    f32x4 sacc[2][4];
#pragma unroll
    for (int rb = 0; rb < 2; ++rb)
#pragma unroll
      for (int ct = 0; ct < 4; ++ct)
#pragma unroll
        for (int r = 0; r < 4; ++r) sacc[rb][ct][r] = 0.f;
#pragma unroll
    for (int ct = 0; ct < 4; ++ct)
#pragma unroll
      for (int kc = 0; kc < 4; ++kc) {
        bf16x8 bk = *(const bf16x8*)&ksb[(ct * 4 + kc) * 512 + lane * 8];
        sacc[0][ct] = __builtin_amdgcn_mfma_f32_16x16x32_bf16(aq[0][kc], bk, sacc[0][ct], 0, 0, 0);
        sacc[1][ct] = __builtin_amdgcn_mfma_f32_16x16x32_bf16(aq[1][kc], bk, sacc[1][ct], 0, 0, 0);
      }

    // online softmax per row-block; write P in A-op fragment order
#pragma unroll
    for (int rb = 0; rb < 2; ++rb) {
      const int rowb = qb * 128 + wave * 32 + rb * 16 + quad * 4;  // + r
      float p[4][4];
      if (t0 + 63 > rowb) {
#pragma unroll
        for (int ct = 0; ct < 4; ++ct) {
          const int kcol = t0 + ct * 16 + lo;
#pragma unroll
          for (int r = 0; r < 4; ++r)
            p[ct][r] = (kcol > rowb + r) ? -INFINITY : sacc[rb][ct][r] * scale;
        }
      } else {
#pragma unroll
        for (int ct = 0; ct < 4; ++ct)
#pragma unroll
          for (int r = 0; r < 4; ++r) p[ct][r] = sacc[rb][ct][r] * scale;
      }
      float mx[4], al[4], ls[4];
#pragma unroll
      for (int r = 0; r < 4; ++r)
        mx[r] = fmaxf(fmaxf(p[0][r], p[1][r]), fmaxf(p[2][r], p[3][r]));
#pragma unroll
      for (int mm = 1; mm < 16; mm <<= 1)
#pragma unroll
        for (int r = 0; r < 4; ++r)
          mx[r] = fmaxf(mx[r], __shfl_xor(mx[r], mm, 64));
#pragma unroll
      for (int r = 0; r < 4; ++r) {
        const float mn = fmaxf(m_run[rb][r], mx[r]);
        al[r] = __expf(m_run[rb][r] - mn);
        m_run[rb][r] = mn;
        float sum = 0.f;
#pragma unroll
        for (int ct = 0; ct < 4; ++ct) {
          p[ct][r] = __expf(p[ct][r] - mn);
          sum += p[ct][r];
        }
        ls[r] = sum;
      }
#pragma unroll
      for (int mm = 1; mm < 16; mm <<= 1)
#pragma unroll
        for (int r = 0; r < 4; ++r) ls[r] += __shfl_xor(ls[r], mm, 64);
#pragma unroll
      for (int r = 0; r < 4; ++r) l_run[rb][r] = al[r] * l_run[rb][r] + ls[r];

      // P scatter: element (m=quad*4+r, kv=ct*16+lo) -> A-frag chunk order
#pragma unroll
      for (int ct = 0; ct < 4; ++ct) {
        const int kvc = ct * 16 + lo;
        const int idx = (rb * 2 + (kvc >> 5)) * 512 + ((kvc >> 3) & 3) * 128 + quad * 32 + (kvc & 7);
#pragma unroll
        for (int r = 0; r < 4; ++r) Pw[idx + r * 8] = f2bf(p[ct][r]);
      }
      // rescale O accumulator
#pragma unroll
      for (int dt = 0; dt < 8; ++dt)
#pragma unroll
        for (int r = 0; r < 4; ++r) oacc[rb][dt][r] *= al[r];
    }

    // O += P @ V: 32 MFMAs, 16 V-frag reads (reused across row-blocks)
    bf16x8 ap[2][2];
#pragma unroll
    for (int rb = 0; rb < 2; ++rb)
#pragma unroll
      for (int k2 = 0; k2 < 2; ++k2)
        ap[rb][k2] = *(const bf16x8*)&Pw[(rb * 2 + k2) * 512 + lane * 8];
#pragma unroll
    for (int dt = 0; dt < 8; ++dt)
#pragma unroll
      for (int k2 = 0; k2 < 2; ++k2) {
        bf16x8 bv = *(const bf16x8*)&vsb[(dt * 2 + k2) * 512 + lane * 8];
        oacc[0][dt] = __builtin_amdgcn_mfma_f32_16x16x32_bf16(ap[0][k2], bv, oacc[0][dt], 0, 0, 0);
        oacc[1][dt] = __builtin_amdgcn_mfma_f32_16x16x32_bf16(ap[1][k2], bv, oacc[1][dt], 0, 0, 0);
      }
  }

  // epilogue: Y[(b*T + row) * C + h*128 + d] bf16
#pragma unroll
  for (int rb = 0; rb < 2; ++rb) {
    float inv[4];
#pragma unroll
    for (int r = 0; r < 4; ++r) inv[r] = 1.f / l_run[rb][r];
    const size_t row0 = (size_t)b * TT + qb * 128 + wave * 32 + rb * 16 + quad * 4;
#pragma unroll
    for (int dt = 0; dt < 8; ++dt)
#pragma unroll
      for (int r = 0; r < 4; ++r)
        Y[(row0 + r) * CC + h * HD + dt * 16 + lo] = f2bf(oacc[rb][dt][r] * inv[r]);
  }
}

// ---------------------------------------------------------------------------
// kernel_launch. ws layout (bytes):
//   [0,16M):   xb (bf16 x)        -> later qb_buf (bf16 q, B,H,T,D)
//   [16M,28M): Wt (bf16 qkv^T)    -> later kb (4M) + vt (8M)
//   [28M,76M): qkv_lin fp32       -> first 16M later y (bf16, M x C)
//   [76M,84M): Wot (bf16 Wo^T)
// ---------------------------------------------------------------------------
extern "C" void kernel_launch(void* const* d_in, const int* in_sizes, int n_in,
                              void* d_out, int out_size, void* d_ws, size_t ws_size,
                              hipStream_t stream) {
  (void)in_sizes; (void)n_in; (void)out_size; (void)ws_size;
  const float* x    = (const float*)d_in[0];
  const float* cosp = (const float*)d_in[1];
  const float* sinp = (const float*)d_in[2];
  const float* Wq   = (const float*)d_in[3];
  const float* Wk   = (const float*)d_in[4];
  const float* Wv   = (const float*)d_in[5];
  const float* Wo   = (const float*)d_in[6];
  const float* bo   = (const float*)d_in[7];
  float* out = (float*)d_out;
  char* ws = (char*)d_ws;

  const size_t MB = 1024 * 1024;
  u16*   xb      = (u16*)(ws);
  u16*   Wt      = (u16*)(ws + 16 * MB);
  float* qkv_lin = (float*)(ws + 28 * MB);
  u16*   Wot     = (u16*)(ws + 76 * MB);
  u16*   qb_buf  = (u16*)(ws);             // alias xb (dead after GEMM1)
  u16*   kb      = (u16*)(ws + 16 * MB);   // alias Wt
  u16*   vt      = (u16*)(ws + 20 * MB);   // alias Wt+4M
  u16*   y       = (u16*)(ws + 28 * MB);   // alias qkv_lin head

  // 1. x -> bf16
  convert_bf16<<<(MTOT * CC / 8 + 255) / 256, 256, 0, stream>>>(x, xb, MTOT * CC / 8);

  // 2. weight transposes -> bf16
  transpose_w<<<dim3(CC / 32, CC / 32), dim3(32, 8), 0, stream>>>(Wq, Wt, CC, 0);
  transpose_w<<<dim3(NKV * HD / 32, CC / 32), dim3(32, 8), 0, stream>>>(Wk, Wt, NKV * HD, CC);
  transpose_w<<<dim3(NKV * HD / 32, CC / 32), dim3(32, 8), 0, stream>>>(Wv, Wt, NKV * HD, CC + NKV * HD);
  transpose_w<<<dim3(CC / 32, CC / 32), dim3(32, 8), 0, stream>>>(Wo, Wot, CC, 0);

  // 3. fused QKV GEMM: (M=4096, N=3072, K=2048) fp32 out
  gemm_bt_bf16<<<dim3(NQKV / 128, MTOT / 128), 256, 0, stream>>>(
      xb, Wt, nullptr, qkv_lin, MTOT, NQKV, CC);

  // 4. RMSNorm + RoPE -> bf16 q/k head-major (wave per head)
  qkv_post<<<dim3(MTOT, 5), 256, 0, stream>>>(qkv_lin, cosp, sinp, qb_buf, kb);

  // 5. V -> (B,KV,D,T) bf16
  v_transpose<<<dim3(TT / 32, HD / 32, BB * NKV), dim3(32, 8), 0, stream>>>(qkv_lin, vt);

  // 6. MFMA flash attention v2 -> y bf16 (M x C)
  attn_mfma<<<dim3(16, BB * NH), 256, 0, stream>>>(qb_buf, kb, vt, y);

  // 7. out-proj GEMM + bias: (M=4096, N=2048, K=2048) fp32 out
  gemm_bt_bf16<<<dim3(CC / 128, MTOT / 128), 256, 0, stream>>>(
      y, Wot, bo, out, MTOT, CC, CC);
}

// Round 4
// 368.804 us; speedup vs baseline: 9.7978x; 1.1116x over previous
//
#include <hip/hip_runtime.h>
#include <hip/hip_bf16.h>
#include <math.h>

// Problem constants (B=2, T=2048, C=2048, NH=16, NKV=4, D=128, HALF=64)
#define BB 2
#define TT 2048
#define CC 2048
#define NH 16
#define NKV 4
#define HD 128
#define HALF 64
#define MTOT (BB*TT)            // 4096
#define NQKV (CC + 2*NKV*HD)    // 3072 (fused q|k|v columns)

typedef unsigned short u16;
typedef __attribute__((ext_vector_type(8))) short bf16x8;
typedef __attribute__((ext_vector_type(4))) float f32x4;

// fp32 -> bf16 (round-to-nearest-even)
__device__ __forceinline__ u16 f2bf(float f) {
  unsigned u = __float_as_uint(f);
  unsigned r = (u + 0x7FFFu + ((u >> 16) & 1u)) >> 16;
  return (u16)r;
}

// async global->LDS, 16B per lane; lds base must be wave-uniform (HW adds lane*16)
__device__ __forceinline__ void gl_lds16(const void* g, void* l) {
  __builtin_amdgcn_global_load_lds(
      (const __attribute__((address_space(1))) unsigned int*)g,
      (__attribute__((address_space(3))) unsigned int*)l, 16, 0, 0);
}

// ---------------------------------------------------------------------------
// x (fp32) -> bf16, 8 elems/thread
// ---------------------------------------------------------------------------
__global__ __launch_bounds__(256) void convert_bf16(
    const float* __restrict__ src, u16* __restrict__ dst, int n8) {
  int i = blockIdx.x * 256 + threadIdx.x;
  if (i >= n8) return;
  const float4* s4 = (const float4*)src;
  float4 a = s4[(size_t)i * 2], b = s4[(size_t)i * 2 + 1];
  bf16x8 o;
  o[0] = (short)f2bf(a.x); o[1] = (short)f2bf(a.y);
  o[2] = (short)f2bf(a.z); o[3] = (short)f2bf(a.w);
  o[4] = (short)f2bf(b.x); o[5] = (short)f2bf(b.y);
  o[6] = (short)f2bf(b.z); o[7] = (short)f2bf(b.w);
  ((bf16x8*)dst)[i] = o;
}

// ---------------------------------------------------------------------------
// W (K=2048 rows, N cols, fp32) -> Wt[(row_off+n)*2048 + k] bf16 (transposed)
// ---------------------------------------------------------------------------
__global__ __launch_bounds__(256) void transpose_w(
    const float* __restrict__ W, u16* __restrict__ Wt, int N, int row_off) {
  __shared__ float tile[32][33];
  const int n0 = blockIdx.x * 32, k0 = blockIdx.y * 32;
  const int tx = threadIdx.x, ty = threadIdx.y;
#pragma unroll
  for (int i = 0; i < 4; ++i)
    tile[ty + 8 * i][tx] = W[(size_t)(k0 + ty + 8 * i) * N + n0 + tx];
  __syncthreads();
#pragma unroll
  for (int i = 0; i < 4; ++i)
    Wt[(size_t)(row_off + n0 + ty + 8 * i) * CC + k0 + tx] =
        f2bf(tile[tx][ty + 8 * i]);
}

// ---------------------------------------------------------------------------
// v part of qkv_lin (fp32) -> vt (B,KV,D,T) bf16
// ---------------------------------------------------------------------------
__global__ __launch_bounds__(256) void v_transpose(
    const float* __restrict__ qkv_lin, u16* __restrict__ vt) {
  __shared__ float tile[32][33];
  const int t0 = blockIdx.x * 32, d0 = blockIdx.y * 32;
  const int p = blockIdx.z;             // b*NKV + kv
  const int b = p >> 2, kv = p & 3;
  const int tx = threadIdx.x, ty = threadIdx.y;
#pragma unroll
  for (int i = 0; i < 4; ++i)
    tile[ty + 8 * i][tx] =
        qkv_lin[(size_t)(b * TT + t0 + ty + 8 * i) * NQKV + CC + NKV * HD + kv * HD + d0 + tx];
  __syncthreads();
#pragma unroll
  for (int i = 0; i < 4; ++i)
    vt[((size_t)p * HD + d0 + ty + 8 * i) * TT + t0 + tx] =
        f2bf(tile[tx][ty + 8 * i]);
}

// ---------------------------------------------------------------------------
// bf16 MFMA GEMM (m97 structure), unchanged (known good).
// ---------------------------------------------------------------------------
__global__ __launch_bounds__(256) void gemm_bt_bf16(
    const u16* __restrict__ A, const u16* __restrict__ Bt,
    const float* __restrict__ bias, float* __restrict__ C,
    int M, int N, int K) {
  __shared__ u16 As[128 * 32];
  __shared__ u16 Bs[128 * 32];
  const int tid = threadIdx.x;
  const int wave = tid >> 6, lane = tid & 63;
  const int quad = lane >> 4, lo = lane & 15;
  const int bm = blockIdx.y * 128, bn = blockIdx.x * 128;
  const int wm = (wave & 1) * 64, wn = (wave >> 1) * 64;

  f32x4 acc[4][4];
#pragma unroll
  for (int i = 0; i < 4; ++i)
#pragma unroll
    for (int j = 0; j < 4; ++j)
#pragma unroll
      for (int r = 0; r < 4; ++r) acc[i][j][r] = 0.f;

  const int iss0 = wave * 2, iss1 = wave * 2 + 1;
  const int e0 = iss0 * 512 + lane * 8, e1 = iss1 * 512 + lane * 8;
  const int r0 = e0 >> 5, c0 = e0 & 31;
  const int r1 = e1 >> 5, c1 = e1 & 31;

  for (int k0 = 0; k0 < K; k0 += 32) {
    gl_lds16(A + (size_t)(bm + r0) * K + k0 + c0, (char*)As + iss0 * 1024);
    gl_lds16(A + (size_t)(bm + r1) * K + k0 + c1, (char*)As + iss1 * 1024);
    gl_lds16(Bt + (size_t)(bn + r0) * K + k0 + c0, (char*)Bs + iss0 * 1024);
    gl_lds16(Bt + (size_t)(bn + r1) * K + k0 + c1, (char*)Bs + iss1 * 1024);
    __syncthreads();

    bf16x8 af[4], bg[4];
#pragma unroll
    for (int i = 0; i < 4; ++i)
      af[i] = *(const bf16x8*)&As[(wm + i * 16 + lo) * 32 + quad * 8];
#pragma unroll
    for (int j = 0; j < 4; ++j)
      bg[j] = *(const bf16x8*)&Bs[(wn + j * 16 + lo) * 32 + quad * 8];
#pragma unroll
    for (int i = 0; i < 4; ++i)
#pragma unroll
      for (int j = 0; j < 4; ++j)
        acc[i][j] = __builtin_amdgcn_mfma_f32_16x16x32_bf16(af[i], bg[j], acc[i][j], 0, 0, 0);
    __syncthreads();
  }

#pragma unroll
  for (int i = 0; i < 4; ++i)
#pragma unroll
    for (int j = 0; j < 4; ++j)
#pragma unroll
      for (int r = 0; r < 4; ++r) {
        int row = bm + wm + i * 16 + quad * 4 + r;
        int col = bn + wn + j * 16 + lo;
        float v = acc[i][j][r];
        if (bias) v += bias[col];
        C[(size_t)row * N + col] = v;
      }
}

// ---------------------------------------------------------------------------
// RMSNorm + RoPE, one wave per (b,t,head). grid (B*T, 5), block 256 (4 waves).
// ---------------------------------------------------------------------------
__global__ __launch_bounds__(256) void qkv_post(
    const float* __restrict__ qkv_lin, const float* __restrict__ cosp,
    const float* __restrict__ sinp, u16* __restrict__ q, u16* __restrict__ k) {
  const int bt = blockIdx.x;
  const int hh = blockIdx.y * 4 + (threadIdx.x >> 6);   // 0..19
  const int lane = threadIdx.x & 63;
  const int t = bt & (TT - 1), b = bt >> 11;
  const int col = (hh < NH) ? hh * HD : CC + (hh - NH) * HD;
  const float* src = qkv_lin + (size_t)bt * NQKV + col;
  float v1 = src[lane], v2 = src[lane + 64];
  float ss = v1 * v1 + v2 * v2;
#pragma unroll
  for (int mm = 1; mm < 64; mm <<= 1) ss += __shfl_xor(ss, mm, 64);
  float rms = rsqrtf(ss * (1.f / 128.f) + 1.1920929e-7f);
  float c = cosp[t * HALF + lane], s = sinp[t * HALF + lane];
  float o1 = v1 * rms * c - v2 * rms * s;
  float o2 = v1 * rms * s + v2 * rms * c;
  if (hh < NH) {
    u16* dst = q + (((size_t)(b * NH + hh)) * TT + t) * HD;
    dst[lane] = f2bf(o1); dst[lane + 64] = f2bf(o2);
  } else {
    u16* dst = k + (((size_t)(b * NKV + (hh - NH))) * TT + t) * HD;
    dst[lane] = f2bf(o1); dst[lane + 64] = f2bf(o2);
  }
}

// ---------------------------------------------------------------------------
// online-softmax update for one 16-row block (C/D-layout sacc[4] = 4 col-tiles)
// ---------------------------------------------------------------------------
__device__ __forceinline__ void softmax_rb(
    const f32x4* sacc, float* m_run, float* l_run, f32x4* oacc,
    u16* Pdst, int rowb, int t0, int lo, int quad) {
  const float scale = 0.08838834764831845f;   // 1/sqrt(128)
  float p[4][4];
  if (t0 + 63 > rowb) {
#pragma unroll
    for (int ct = 0; ct < 4; ++ct) {
      const int kcol = t0 + ct * 16 + lo;
#pragma unroll
      for (int r = 0; r < 4; ++r)
        p[ct][r] = (kcol > rowb + r) ? -INFINITY : sacc[ct][r] * scale;
    }
  } else {
#pragma unroll
    for (int ct = 0; ct < 4; ++ct)
#pragma unroll
      for (int r = 0; r < 4; ++r) p[ct][r] = sacc[ct][r] * scale;
  }
  float mx[4], al[4], ls[4];
#pragma unroll
  for (int r = 0; r < 4; ++r)
    mx[r] = fmaxf(fmaxf(p[0][r], p[1][r]), fmaxf(p[2][r], p[3][r]));
#pragma unroll
  for (int mm = 1; mm < 16; mm <<= 1)
#pragma unroll
    for (int r = 0; r < 4; ++r)
      mx[r] = fmaxf(mx[r], __shfl_xor(mx[r], mm, 64));
#pragma unroll
  for (int r = 0; r < 4; ++r) {
    const float mn = fmaxf(m_run[r], mx[r]);
    al[r] = __expf(m_run[r] - mn);
    m_run[r] = mn;
    float sum = 0.f;
#pragma unroll
    for (int ct = 0; ct < 4; ++ct) {
      p[ct][r] = __expf(p[ct][r] - mn);
      sum += p[ct][r];
    }
    ls[r] = sum;
  }
#pragma unroll
  for (int mm = 1; mm < 16; mm <<= 1)
#pragma unroll
    for (int r = 0; r < 4; ++r) ls[r] += __shfl_xor(ls[r], mm, 64);
#pragma unroll
  for (int r = 0; r < 4; ++r) l_run[r] = al[r] * l_run[r] + ls[r];
  // scatter P element (m=quad*4+r, kv=ct*16+lo) into A-op fragment order
#pragma unroll
  for (int ct = 0; ct < 4; ++ct) {
    const int kvc = ct * 16 + lo;
    const int idx = (kvc >> 5) * 512 + ((kvc >> 3) & 3) * 128 + quad * 32 + (kvc & 7);
#pragma unroll
    for (int r = 0; r < 4; ++r) Pdst[idx + r * 8] = f2bf(p[ct][r]);
  }
  // rescale O accumulator
#pragma unroll
  for (int dt = 0; dt < 8; ++dt)
#pragma unroll
    for (int r = 0; r < 4; ++r) oacc[dt][r] *= al[r];
}

// ---------------------------------------------------------------------------
// MFMA flash attention v3: complementary q-tile pairing, 64 KB LDS.
// grid (16, 32), block 256 (4 waves). Block owns q-tiles qt and 31-qt
// (64 rows each); wave = 16 rows of each (rb=0 -> tile A=qt, rb=1 -> tile
// B=31-qt). KV passes nt=0..31-qt; rb=0 active only while nt<=qt -> every
// block does exactly 33 quanta of work (perfect causal balance).
// K double-buffered (32K), V single-buffered (16K), P wave-private (16K):
// 64 KB total -> 2 blocks/CU. Two barriers/pass: stage V(nt)+K(nt+1) after
// barrier1, QK+softmax cover the load latency, barrier2 drains vmcnt -> PV.
// ---------------------------------------------------------------------------
__global__ __launch_bounds__(256, 2) void attn_mfma(
    const u16* __restrict__ Qb, const u16* __restrict__ Kb,
    const u16* __restrict__ Vt, u16* __restrict__ Y) {
  __shared__ u16 Ks[2][8192];   // 16 sets (ct*4+kc) x 512, double-buffered
  __shared__ u16 Vs[8192];      // 16 sets (dt*2+k2) x 512, single-buffered
  __shared__ u16 Ps[4][2048];   // per wave: 4 sets (rb*2+k2) x 512

  const int qt = blockIdx.x;    // pair (qt, 31-qt), qt in 0..15
  const int bh = blockIdx.y;
  const int b = bh >> 4, h = bh & 15, kvh = h >> 2;
  const int tid = threadIdx.x;
  const int wave = tid >> 6, lane = tid & 63;
  const int quad = lane >> 4, lo = lane & 15;

  const int rowsA = qt * 64;
  const int rowsB = (31 - qt) * 64;
  const u16* Qg = Qb + (size_t)(b * NH + h) * TT * HD;
  const u16* Kg = Kb + (size_t)(b * NKV + kvh) * TT * HD;
  const u16* Vg = Vt + (size_t)(b * NKV + kvh) * HD * TT;

  // Q fragments (A-op: m=lo, k=quad*8+j): rb=0 tile A, rb=1 tile B
  bf16x8 aq[2][4];
#pragma unroll
  for (int kc = 0; kc < 4; ++kc) {
    aq[0][kc] = *(const bf16x8*)(Qg + (size_t)(rowsA + wave * 16 + lo) * HD + kc * 32 + quad * 8);
    aq[1][kc] = *(const bf16x8*)(Qg + (size_t)(rowsB + wave * 16 + lo) * HD + kc * 32 + quad * 8);
  }

  // staging pointers: wave stages sets wave*4..wave*4+3 for K and V
  const u16* kgp[4]; const u16* vgp[4];
  u16* klp[2][4]; u16* vlp[4];
#pragma unroll
  for (int c = 0; c < 4; ++c) {
    const int s = wave * 4 + c;
    const int ct = s >> 2, kq = s & 3;
    kgp[c] = Kg + (size_t)(ct * 16 + lo) * HD + kq * 32 + quad * 8;
    const int dt = s >> 1, k2 = s & 1;
    vgp[c] = Vg + (size_t)(dt * 16 + lo) * TT + k2 * 32 + quad * 8;
    klp[0][c] = &Ks[0][s * 512]; klp[1][c] = &Ks[1][s * 512];
    vlp[c] = &Vs[s * 512];
  }

  f32x4 oacc[2][8];
#pragma unroll
  for (int rb = 0; rb < 2; ++rb)
#pragma unroll
    for (int dt = 0; dt < 8; ++dt)
#pragma unroll
      for (int r = 0; r < 4; ++r) oacc[rb][dt][r] = 0.f;
  float m_run[2][4], l_run[2][4];
#pragma unroll
  for (int rb = 0; rb < 2; ++rb)
#pragma unroll
    for (int r = 0; r < 4; ++r) { m_run[rb][r] = -INFINITY; l_run[rb][r] = 0.f; }

  u16* Pw = Ps[wave];
  const int ntiles = 32 - qt;   // kv tiles for heavy member (tile B)

  // prologue: stage K(0) -> buf 0
#pragma unroll
  for (int c = 0; c < 4; ++c) { gl_lds16(kgp[c], klp[0][c]); kgp[c] += 64 * HD; }

  for (int nt = 0; nt < ntiles; ++nt) {
    const int par = nt & 1;
    __syncthreads();   // K(nt) landed (vmcnt drained); PV(nt-1) V-reads done
    // stage V(nt) (single buf) and prefetch K(nt+1) (other K buf)
#pragma unroll
    for (int c = 0; c < 4; ++c) { gl_lds16(vgp[c], vlp[c]); vgp[c] += 64; }
    if (nt + 1 < ntiles) {
#pragma unroll
      for (int c = 0; c < 4; ++c) { gl_lds16(kgp[c], klp[par ^ 1][c]); kgp[c] += 64 * HD; }
    }
    const u16* ksb = Ks[par];
    const int t0 = nt * 64;
    const bool act0 = (nt <= qt);

    // S = Q K^T
    f32x4 sacc[2][4];
#pragma unroll
    for (int rb = 0; rb < 2; ++rb)
#pragma unroll
      for (int ct = 0; ct < 4; ++ct)
#pragma unroll
        for (int r = 0; r < 4; ++r) sacc[rb][ct][r] = 0.f;
    if (act0) {
#pragma unroll
      for (int ct = 0; ct < 4; ++ct)
#pragma unroll
        for (int kc = 0; kc < 4; ++kc) {
          bf16x8 bk = *(const bf16x8*)&ksb[(ct * 4 + kc) * 512 + lane * 8];
          sacc[0][ct] = __builtin_amdgcn_mfma_f32_16x16x32_bf16(aq[0][kc], bk, sacc[0][ct], 0, 0, 0);
          sacc[1][ct] = __builtin_amdgcn_mfma_f32_16x16x32_bf16(aq[1][kc], bk, sacc[1][ct], 0, 0, 0);
        }
    } else {
#pragma unroll
      for (int ct = 0; ct < 4; ++ct)
#pragma unroll
        for (int kc = 0; kc < 4; ++kc) {
          bf16x8 bk = *(const bf16x8*)&ksb[(ct * 4 + kc) * 512 + lane * 8];
          sacc[1][ct] = __builtin_amdgcn_mfma_f32_16x16x32_bf16(aq[1][kc], bk, sacc[1][ct], 0, 0, 0);
        }
    }

    // softmax (tile B always; tile A while active)
    softmax_rb(sacc[1], m_run[1], l_run[1], oacc[1], Pw + 1024,
               rowsB + wave * 16 + quad * 4, t0, lo, quad);
    if (act0)
      softmax_rb(sacc[0], m_run[0], l_run[0], oacc[0], Pw,
                 rowsA + wave * 16 + quad * 4, t0, lo, quad);

    __syncthreads();   // drains vmcnt -> V(nt) staged by all waves is ready

    // O += P @ V
    if (act0) {
      bf16x8 ap0[2], ap1[2];
#pragma unroll
      for (int k2 = 0; k2 < 2; ++k2) {
        ap0[k2] = *(const bf16x8*)&Pw[k2 * 512 + lane * 8];
        ap1[k2] = *(const bf16x8*)&Pw[(2 + k2) * 512 + lane * 8];
      }
#pragma unroll
      for (int dt = 0; dt < 8; ++dt)
#pragma unroll
        for (int k2 = 0; k2 < 2; ++k2) {
          bf16x8 bv = *(const bf16x8*)&Vs[(dt * 2 + k2) * 512 + lane * 8];
          oacc[0][dt] = __builtin_amdgcn_mfma_f32_16x16x32_bf16(ap0[k2], bv, oacc[0][dt], 0, 0, 0);
          oacc[1][dt] = __builtin_amdgcn_mfma_f32_16x16x32_bf16(ap1[k2], bv, oacc[1][dt], 0, 0, 0);
        }
    } else {
      bf16x8 ap1[2];
#pragma unroll
      for (int k2 = 0; k2 < 2; ++k2)
        ap1[k2] = *(const bf16x8*)&Pw[(2 + k2) * 512 + lane * 8];
#pragma unroll
      for (int dt = 0; dt < 8; ++dt)
#pragma unroll
        for (int k2 = 0; k2 < 2; ++k2) {
          bf16x8 bv = *(const bf16x8*)&Vs[(dt * 2 + k2) * 512 + lane * 8];
          oacc[1][dt] = __builtin_amdgcn_mfma_f32_16x16x32_bf16(ap1[k2], bv, oacc[1][dt], 0, 0, 0);
        }
    }
  }

  // epilogue: Y[(b*T + row) * C + h*128 + d] bf16
#pragma unroll
  for (int rb = 0; rb < 2; ++rb) {
    const int rows = (rb == 0) ? rowsA : rowsB;
    float inv[4];
#pragma unroll
    for (int r = 0; r < 4; ++r) inv[r] = 1.f / l_run[rb][r];
    const size_t row0 = (size_t)b * TT + rows + wave * 16 + quad * 4;
#pragma unroll
    for (int dt = 0; dt < 8; ++dt)
#pragma unroll
      for (int r = 0; r < 4; ++r)
        Y[(row0 + r) * CC + h * HD + dt * 16 + lo] = f2bf(oacc[rb][dt][r] * inv[r]);
  }
}

// ---------------------------------------------------------------------------
// kernel_launch. ws layout (bytes):
//   [0,16M):   xb (bf16 x)        -> later qb_buf (bf16 q, B,H,T,D)
//   [16M,28M): Wt (bf16 qkv^T)    -> later kb (4M) + vt (8M)
//   [28M,76M): qkv_lin fp32       -> first 16M later y (bf16, M x C)
//   [76M,84M): Wot (bf16 Wo^T)
// ---------------------------------------------------------------------------
extern "C" void kernel_launch(void* const* d_in, const int* in_sizes, int n_in,
                              void* d_out, int out_size, void* d_ws, size_t ws_size,
                              hipStream_t stream) {
  (void)in_sizes; (void)n_in; (void)out_size; (void)ws_size;
  const float* x    = (const float*)d_in[0];
  const float* cosp = (const float*)d_in[1];
  const float* sinp = (const float*)d_in[2];
  const float* Wq   = (const float*)d_in[3];
  const float* Wk   = (const float*)d_in[4];
  const float* Wv   = (const float*)d_in[5];
  const float* Wo   = (const float*)d_in[6];
  const float* bo   = (const float*)d_in[7];
  float* out = (float*)d_out;
  char* ws = (char*)d_ws;

  const size_t MB = 1024 * 1024;
  u16*   xb      = (u16*)(ws);
  u16*   Wt      = (u16*)(ws + 16 * MB);
  float* qkv_lin = (float*)(ws + 28 * MB);
  u16*   Wot     = (u16*)(ws + 76 * MB);
  u16*   qb_buf  = (u16*)(ws);             // alias xb (dead after GEMM1)
  u16*   kb      = (u16*)(ws + 16 * MB);   // alias Wt
  u16*   vt      = (u16*)(ws + 20 * MB);   // alias Wt+4M
  u16*   y       = (u16*)(ws + 28 * MB);   // alias qkv_lin head

  // 1. x -> bf16
  convert_bf16<<<(MTOT * CC / 8 + 255) / 256, 256, 0, stream>>>(x, xb, MTOT * CC / 8);

  // 2. weight transposes -> bf16
  transpose_w<<<dim3(CC / 32, CC / 32), dim3(32, 8), 0, stream>>>(Wq, Wt, CC, 0);
  transpose_w<<<dim3(NKV * HD / 32, CC / 32), dim3(32, 8), 0, stream>>>(Wk, Wt, NKV * HD, CC);
  transpose_w<<<dim3(NKV * HD / 32, CC / 32), dim3(32, 8), 0, stream>>>(Wv, Wt, NKV * HD, CC + NKV * HD);
  transpose_w<<<dim3(CC / 32, CC / 32), dim3(32, 8), 0, stream>>>(Wo, Wot, CC, 0);

  // 3. fused QKV GEMM: (M=4096, N=3072, K=2048) fp32 out
  gemm_bt_bf16<<<dim3(NQKV / 128, MTOT / 128), 256, 0, stream>>>(
      xb, Wt, nullptr, qkv_lin, MTOT, NQKV, CC);

  // 4. RMSNorm + RoPE -> bf16 q/k head-major (wave per head)
  qkv_post<<<dim3(MTOT, 5), 256, 0, stream>>>(qkv_lin, cosp, sinp, qb_buf, kb);

  // 5. V -> (B,KV,D,T) bf16
  v_transpose<<<dim3(TT / 32, HD / 32, BB * NKV), dim3(32, 8), 0, stream>>>(qkv_lin, vt);

  // 6. MFMA flash attention v3 (paired q-tiles) -> y bf16 (M x C)
  attn_mfma<<<dim3(16, BB * NH), 256, 0, stream>>>(qb_buf, kb, vt, y);

  // 7. out-proj GEMM + bias: (M=4096, N=2048, K=2048) fp32 out
  gemm_bt_bf16<<<dim3(CC / 128, MTOT / 128), 256, 0, stream>>>(
      y, Wot, bo, out, MTOT, CC, CC);
}

// Round 5
// 345.440 us; speedup vs baseline: 10.4605x; 1.0676x over previous
//
#include <hip/hip_runtime.h>
#include <hip/hip_bf16.h>
#include <math.h>

// Problem constants (B=2, T=2048, C=2048, NH=16, NKV=4, D=128, HALF=64)
#define BB 2
#define TT 2048
#define CC 2048
#define NH 16
#define NKV 4
#define HD 128
#define HALF 64
#define MTOT (BB*TT)            // 4096
#define NQKV (CC + 2*NKV*HD)    // 3072 (fused q|k|v columns)

typedef unsigned short u16;
typedef __attribute__((ext_vector_type(8))) short bf16x8;
typedef __attribute__((ext_vector_type(4))) float f32x4;

// fp32 -> bf16 (round-to-nearest-even)
__device__ __forceinline__ u16 f2bf(float f) {
  unsigned u = __float_as_uint(f);
  unsigned r = (u + 0x7FFFu + ((u >> 16) & 1u)) >> 16;
  return (u16)r;
}

// async global->LDS, 16B per lane; lds base must be wave-uniform (HW adds lane*16)
__device__ __forceinline__ void gl_lds16(const void* g, void* l) {
  __builtin_amdgcn_global_load_lds(
      (const __attribute__((address_space(1))) unsigned int*)g,
      (__attribute__((address_space(3))) unsigned int*)l, 16, 0, 0);
}

// ---------------------------------------------------------------------------
// x (fp32) -> bf16, 8 elems/thread
// ---------------------------------------------------------------------------
__global__ __launch_bounds__(256) void convert_bf16(
    const float* __restrict__ src, u16* __restrict__ dst, int n8) {
  int i = blockIdx.x * 256 + threadIdx.x;
  if (i >= n8) return;
  const float4* s4 = (const float4*)src;
  float4 a = s4[(size_t)i * 2], b = s4[(size_t)i * 2 + 1];
  bf16x8 o;
  o[0] = (short)f2bf(a.x); o[1] = (short)f2bf(a.y);
  o[2] = (short)f2bf(a.z); o[3] = (short)f2bf(a.w);
  o[4] = (short)f2bf(b.x); o[5] = (short)f2bf(b.y);
  o[6] = (short)f2bf(b.z); o[7] = (short)f2bf(b.w);
  ((bf16x8*)dst)[i] = o;
}

// ---------------------------------------------------------------------------
// W (K=2048 rows, N cols, fp32) -> Wt[(row_off+n)*2048 + k] bf16 (transposed)
// ---------------------------------------------------------------------------
__global__ __launch_bounds__(256) void transpose_w(
    const float* __restrict__ W, u16* __restrict__ Wt, int N, int row_off) {
  __shared__ float tile[32][33];
  const int n0 = blockIdx.x * 32, k0 = blockIdx.y * 32;
  const int tx = threadIdx.x, ty = threadIdx.y;
#pragma unroll
  for (int i = 0; i < 4; ++i)
    tile[ty + 8 * i][tx] = W[(size_t)(k0 + ty + 8 * i) * N + n0 + tx];
  __syncthreads();
#pragma unroll
  for (int i = 0; i < 4; ++i)
    Wt[(size_t)(row_off + n0 + ty + 8 * i) * CC + k0 + tx] =
        f2bf(tile[tx][ty + 8 * i]);
}

// ---------------------------------------------------------------------------
// v part of qkv_lin (fp32) -> vt (B,KV,D,T) bf16
// ---------------------------------------------------------------------------
__global__ __launch_bounds__(256) void v_transpose(
    const float* __restrict__ qkv_lin, u16* __restrict__ vt) {
  __shared__ float tile[32][33];
  const int t0 = blockIdx.x * 32, d0 = blockIdx.y * 32;
  const int p = blockIdx.z;             // b*NKV + kv
  const int b = p >> 2, kv = p & 3;
  const int tx = threadIdx.x, ty = threadIdx.y;
#pragma unroll
  for (int i = 0; i < 4; ++i)
    tile[ty + 8 * i][tx] =
        qkv_lin[(size_t)(b * TT + t0 + ty + 8 * i) * NQKV + CC + NKV * HD + kv * HD + d0 + tx];
  __syncthreads();
#pragma unroll
  for (int i = 0; i < 4; ++i)
    vt[((size_t)p * HD + d0 + ty + 8 * i) * TT + t0 + tx] =
        f2bf(tile[tx][ty + 8 * i]);
}

// ---------------------------------------------------------------------------
// bf16 MFMA GEMM (m97 structure), unchanged (known good).
// ---------------------------------------------------------------------------
__global__ __launch_bounds__(256) void gemm_bt_bf16(
    const u16* __restrict__ A, const u16* __restrict__ Bt,
    const float* __restrict__ bias, float* __restrict__ C,
    int M, int N, int K) {
  __shared__ u16 As[128 * 32];
  __shared__ u16 Bs[128 * 32];
  const int tid = threadIdx.x;
  const int wave = tid >> 6, lane = tid & 63;
  const int quad = lane >> 4, lo = lane & 15;
  const int bm = blockIdx.y * 128, bn = blockIdx.x * 128;
  const int wm = (wave & 1) * 64, wn = (wave >> 1) * 64;

  f32x4 acc[4][4];
#pragma unroll
  for (int i = 0; i < 4; ++i)
#pragma unroll
    for (int j = 0; j < 4; ++j)
#pragma unroll
      for (int r = 0; r < 4; ++r) acc[i][j][r] = 0.f;

  const int iss0 = wave * 2, iss1 = wave * 2 + 1;
  const int e0 = iss0 * 512 + lane * 8, e1 = iss1 * 512 + lane * 8;
  const int r0 = e0 >> 5, c0 = e0 & 31;
  const int r1 = e1 >> 5, c1 = e1 & 31;

  for (int k0 = 0; k0 < K; k0 += 32) {
    gl_lds16(A + (size_t)(bm + r0) * K + k0 + c0, (char*)As + iss0 * 1024);
    gl_lds16(A + (size_t)(bm + r1) * K + k0 + c1, (char*)As + iss1 * 1024);
    gl_lds16(Bt + (size_t)(bn + r0) * K + k0 + c0, (char*)Bs + iss0 * 1024);
    gl_lds16(Bt + (size_t)(bn + r1) * K + k0 + c1, (char*)Bs + iss1 * 1024);
    __syncthreads();

    bf16x8 af[4], bg[4];
#pragma unroll
    for (int i = 0; i < 4; ++i)
      af[i] = *(const bf16x8*)&As[(wm + i * 16 + lo) * 32 + quad * 8];
#pragma unroll
    for (int j = 0; j < 4; ++j)
      bg[j] = *(const bf16x8*)&Bs[(wn + j * 16 + lo) * 32 + quad * 8];
#pragma unroll
    for (int i = 0; i < 4; ++i)
#pragma unroll
      for (int j = 0; j < 4; ++j)
        acc[i][j] = __builtin_amdgcn_mfma_f32_16x16x32_bf16(af[i], bg[j], acc[i][j], 0, 0, 0);
    __syncthreads();
  }

#pragma unroll
  for (int i = 0; i < 4; ++i)
#pragma unroll
    for (int j = 0; j < 4; ++j)
#pragma unroll
      for (int r = 0; r < 4; ++r) {
        int row = bm + wm + i * 16 + quad * 4 + r;
        int col = bn + wn + j * 16 + lo;
        float v = acc[i][j][r];
        if (bias) v += bias[col];
        C[(size_t)row * N + col] = v;
      }
}

// ---------------------------------------------------------------------------
// RMSNorm + RoPE, one wave per (b,t,head). grid (B*T, 5), block 256 (4 waves).
// ---------------------------------------------------------------------------
__global__ __launch_bounds__(256) void qkv_post(
    const float* __restrict__ qkv_lin, const float* __restrict__ cosp,
    const float* __restrict__ sinp, u16* __restrict__ q, u16* __restrict__ k) {
  const int bt = blockIdx.x;
  const int hh = blockIdx.y * 4 + (threadIdx.x >> 6);   // 0..19
  const int lane = threadIdx.x & 63;
  const int t = bt & (TT - 1), b = bt >> 11;
  const int col = (hh < NH) ? hh * HD : CC + (hh - NH) * HD;
  const float* src = qkv_lin + (size_t)bt * NQKV + col;
  float v1 = src[lane], v2 = src[lane + 64];
  float ss = v1 * v1 + v2 * v2;
#pragma unroll
  for (int mm = 1; mm < 64; mm <<= 1) ss += __shfl_xor(ss, mm, 64);
  float rms = rsqrtf(ss * (1.f / 128.f) + 1.1920929e-7f);
  float c = cosp[t * HALF + lane], s = sinp[t * HALF + lane];
  float o1 = v1 * rms * c - v2 * rms * s;
  float o2 = v1 * rms * s + v2 * rms * c;
  if (hh < NH) {
    u16* dst = q + (((size_t)(b * NH + hh)) * TT + t) * HD;
    dst[lane] = f2bf(o1); dst[lane + 64] = f2bf(o2);
  } else {
    u16* dst = k + (((size_t)(b * NKV + (hh - NH))) * TT + t) * HD;
    dst[lane] = f2bf(o1); dst[lane + 64] = f2bf(o2);
  }
}

// ---------------------------------------------------------------------------
// UNNORMALIZED softmax update for one 16-row block. q,k are RMSNormed
// (L2 norm = sqrt(128) each, RoPE is a rotation) so |s| <= 128/sqrt(128) =
// 11.32 -> exp(s) in [1.2e-5, 9.9e4]: safe in fp32/bf16 WITHOUT max
// subtraction. No cross-lane reductions, no O rescale; l accumulates
// per-lane, reduced once at the epilogue.
// ---------------------------------------------------------------------------
__device__ __forceinline__ void softmax_rb(
    const f32x4* sacc, float* l_lane, u16* Pdst, int rowb, int t0,
    int lo, int quad) {
  const float cc = 0.12751744050808612f;   // log2(e)/sqrt(128)
  if (t0 + 63 > rowb) {                    // diagonal tile: apply causal mask
#pragma unroll
    for (int ct = 0; ct < 4; ++ct) {
      const int kvc = ct * 16 + lo;
      const int kcol = t0 + kvc;
      const int idx = (kvc >> 5) * 512 + ((kvc >> 3) & 3) * 128 + quad * 32 + (kvc & 7);
#pragma unroll
      for (int r = 0; r < 4; ++r) {
        float e = __builtin_amdgcn_exp2f(sacc[ct][r] * cc);
        if (kcol > rowb + r) e = 0.f;
        l_lane[r] += e;
        Pdst[idx + r * 8] = f2bf(e);
      }
    }
  } else {
#pragma unroll
    for (int ct = 0; ct < 4; ++ct) {
      const int kvc = ct * 16 + lo;
      const int idx = (kvc >> 5) * 512 + ((kvc >> 3) & 3) * 128 + quad * 32 + (kvc & 7);
#pragma unroll
      for (int r = 0; r < 4; ++r) {
        float e = __builtin_amdgcn_exp2f(sacc[ct][r] * cc);
        l_lane[r] += e;
        Pdst[idx + r * 8] = f2bf(e);
      }
    }
  }
}

// ---------------------------------------------------------------------------
// MFMA flash attention v4: complementary q-tile pairing, 64 KB LDS,
// unnormalized softmax (no max/rescale machinery).
// grid (16, 32), block 256 (4 waves). Block owns q-tiles qt and 31-qt
// (64 rows each); wave = 16 rows of each. KV passes nt=0..31-qt; tile A
// active while nt<=qt -> every block does exactly 33 work-quanta.
// K double-buffered (32K), V single-buffered (16K), P wave-private (16K).
// ---------------------------------------------------------------------------
__global__ __launch_bounds__(256, 2) void attn_mfma(
    const u16* __restrict__ Qb, const u16* __restrict__ Kb,
    const u16* __restrict__ Vt, u16* __restrict__ Y) {
  __shared__ u16 Ks[2][8192];   // 16 sets (ct*4+kc) x 512, double-buffered
  __shared__ u16 Vs[8192];      // 16 sets (dt*2+k2) x 512, single-buffered
  __shared__ u16 Ps[4][2048];   // per wave: 4 sets (rb*2+k2) x 512

  const int qt = blockIdx.x;    // pair (qt, 31-qt), qt in 0..15
  const int bh = blockIdx.y;
  const int b = bh >> 4, h = bh & 15, kvh = h >> 2;
  const int tid = threadIdx.x;
  const int wave = tid >> 6, lane = tid & 63;
  const int quad = lane >> 4, lo = lane & 15;

  const int rowsA = qt * 64;
  const int rowsB = (31 - qt) * 64;
  const u16* Qg = Qb + (size_t)(b * NH + h) * TT * HD;
  const u16* Kg = Kb + (size_t)(b * NKV + kvh) * TT * HD;
  const u16* Vg = Vt + (size_t)(b * NKV + kvh) * HD * TT;

  // Q fragments (A-op: m=lo, k=quad*8+j): rb=0 tile A, rb=1 tile B
  bf16x8 aq[2][4];
#pragma unroll
  for (int kc = 0; kc < 4; ++kc) {
    aq[0][kc] = *(const bf16x8*)(Qg + (size_t)(rowsA + wave * 16 + lo) * HD + kc * 32 + quad * 8);
    aq[1][kc] = *(const bf16x8*)(Qg + (size_t)(rowsB + wave * 16 + lo) * HD + kc * 32 + quad * 8);
  }

  // staging pointers: wave stages sets wave*4..wave*4+3 for K and V
  const u16* kgp[4]; const u16* vgp[4];
  u16* klp[2][4]; u16* vlp[4];
#pragma unroll
  for (int c = 0; c < 4; ++c) {
    const int s = wave * 4 + c;
    const int ct = s >> 2, kq = s & 3;
    kgp[c] = Kg + (size_t)(ct * 16 + lo) * HD + kq * 32 + quad * 8;
    const int dt = s >> 1, k2 = s & 1;
    vgp[c] = Vg + (size_t)(dt * 16 + lo) * TT + k2 * 32 + quad * 8;
    klp[0][c] = &Ks[0][s * 512]; klp[1][c] = &Ks[1][s * 512];
    vlp[c] = &Vs[s * 512];
  }

  f32x4 oacc[2][8];
#pragma unroll
  for (int rb = 0; rb < 2; ++rb)
#pragma unroll
    for (int dt = 0; dt < 8; ++dt)
#pragma unroll
      for (int r = 0; r < 4; ++r) oacc[rb][dt][r] = 0.f;
  float l_lane[2][4];
#pragma unroll
  for (int rb = 0; rb < 2; ++rb)
#pragma unroll
    for (int r = 0; r < 4; ++r) l_lane[rb][r] = 0.f;

  u16* Pw = Ps[wave];
  const int ntiles = 32 - qt;   // kv tiles for heavy member (tile B)

  // prologue: stage K(0) -> buf 0
#pragma unroll
  for (int c = 0; c < 4; ++c) { gl_lds16(kgp[c], klp[0][c]); kgp[c] += 64 * HD; }

  for (int nt = 0; nt < ntiles; ++nt) {
    const int par = nt & 1;
    __syncthreads();   // K(nt) landed (vmcnt drained); PV(nt-1) V-reads done
    // stage V(nt) (single buf) and prefetch K(nt+1) (other K buf)
#pragma unroll
    for (int c = 0; c < 4; ++c) { gl_lds16(vgp[c], vlp[c]); vgp[c] += 64; }
    if (nt + 1 < ntiles) {
#pragma unroll
      for (int c = 0; c < 4; ++c) { gl_lds16(kgp[c], klp[par ^ 1][c]); kgp[c] += 64 * HD; }
    }
    const u16* ksb = Ks[par];
    const int t0 = nt * 64;
    const bool act0 = (nt <= qt);

    // S = Q K^T
    f32x4 sacc[2][4];
#pragma unroll
    for (int rb = 0; rb < 2; ++rb)
#pragma unroll
      for (int ct = 0; ct < 4; ++ct)
#pragma unroll
        for (int r = 0; r < 4; ++r) sacc[rb][ct][r] = 0.f;
    if (act0) {
#pragma unroll
      for (int ct = 0; ct < 4; ++ct)
#pragma unroll
        for (int kc = 0; kc < 4; ++kc) {
          bf16x8 bk = *(const bf16x8*)&ksb[(ct * 4 + kc) * 512 + lane * 8];
          sacc[0][ct] = __builtin_amdgcn_mfma_f32_16x16x32_bf16(aq[0][kc], bk, sacc[0][ct], 0, 0, 0);
          sacc[1][ct] = __builtin_amdgcn_mfma_f32_16x16x32_bf16(aq[1][kc], bk, sacc[1][ct], 0, 0, 0);
        }
    } else {
#pragma unroll
      for (int ct = 0; ct < 4; ++ct)
#pragma unroll
        for (int kc = 0; kc < 4; ++kc) {
          bf16x8 bk = *(const bf16x8*)&ksb[(ct * 4 + kc) * 512 + lane * 8];
          sacc[1][ct] = __builtin_amdgcn_mfma_f32_16x16x32_bf16(aq[1][kc], bk, sacc[1][ct], 0, 0, 0);
        }
    }

    // unnormalized softmax (tile B always; tile A while active)
    softmax_rb(sacc[1], l_lane[1], Pw + 1024,
               rowsB + wave * 16 + quad * 4, t0, lo, quad);
    if (act0)
      softmax_rb(sacc[0], l_lane[0], Pw,
                 rowsA + wave * 16 + quad * 4, t0, lo, quad);

    __syncthreads();   // drains vmcnt -> V(nt) staged by all waves is ready

    // O += P @ V
    if (act0) {
      bf16x8 ap0[2], ap1[2];
#pragma unroll
      for (int k2 = 0; k2 < 2; ++k2) {
        ap0[k2] = *(const bf16x8*)&Pw[k2 * 512 + lane * 8];
        ap1[k2] = *(const bf16x8*)&Pw[(2 + k2) * 512 + lane * 8];
      }
#pragma unroll
      for (int dt = 0; dt < 8; ++dt)
#pragma unroll
        for (int k2 = 0; k2 < 2; ++k2) {
          bf16x8 bv = *(const bf16x8*)&Vs[(dt * 2 + k2) * 512 + lane * 8];
          oacc[0][dt] = __builtin_amdgcn_mfma_f32_16x16x32_bf16(ap0[k2], bv, oacc[0][dt], 0, 0, 0);
          oacc[1][dt] = __builtin_amdgcn_mfma_f32_16x16x32_bf16(ap1[k2], bv, oacc[1][dt], 0, 0, 0);
        }
    } else {
      bf16x8 ap1[2];
#pragma unroll
      for (int k2 = 0; k2 < 2; ++k2)
        ap1[k2] = *(const bf16x8*)&Pw[(2 + k2) * 512 + lane * 8];
#pragma unroll
      for (int dt = 0; dt < 8; ++dt)
#pragma unroll
        for (int k2 = 0; k2 < 2; ++k2) {
          bf16x8 bv = *(const bf16x8*)&Vs[(dt * 2 + k2) * 512 + lane * 8];
          oacc[1][dt] = __builtin_amdgcn_mfma_f32_16x16x32_bf16(ap1[k2], bv, oacc[1][dt], 0, 0, 0);
        }
    }
  }

  // epilogue: reduce l across the 16 lo-lanes (rows are (quad,r)), then
  // normalize and write Y[(b*T + row) * C + h*128 + d] bf16
#pragma unroll
  for (int rb = 0; rb < 2; ++rb)
#pragma unroll
    for (int r = 0; r < 4; ++r) {
      float l = l_lane[rb][r];
#pragma unroll
      for (int mm = 1; mm < 16; mm <<= 1) l += __shfl_xor(l, mm, 64);
      l_lane[rb][r] = 1.f / l;
    }
#pragma unroll
  for (int rb = 0; rb < 2; ++rb) {
    const int rows = (rb == 0) ? rowsA : rowsB;
    const size_t row0 = (size_t)b * TT + rows + wave * 16 + quad * 4;
#pragma unroll
    for (int dt = 0; dt < 8; ++dt)
#pragma unroll
      for (int r = 0; r < 4; ++r)
        Y[(row0 + r) * CC + h * HD + dt * 16 + lo] = f2bf(oacc[rb][dt][r] * l_lane[rb][r]);
  }
}

// ---------------------------------------------------------------------------
// kernel_launch. ws layout (bytes):
//   [0,16M):   xb (bf16 x)        -> later qb_buf (bf16 q, B,H,T,D)
//   [16M,28M): Wt (bf16 qkv^T)    -> later kb (4M) + vt (8M)
//   [28M,76M): qkv_lin fp32       -> first 16M later y (bf16, M x C)
//   [76M,84M): Wot (bf16 Wo^T)
// ---------------------------------------------------------------------------
extern "C" void kernel_launch(void* const* d_in, const int* in_sizes, int n_in,
                              void* d_out, int out_size, void* d_ws, size_t ws_size,
                              hipStream_t stream) {
  (void)in_sizes; (void)n_in; (void)out_size; (void)ws_size;
  const float* x    = (const float*)d_in[0];
  const float* cosp = (const float*)d_in[1];
  const float* sinp = (const float*)d_in[2];
  const float* Wq   = (const float*)d_in[3];
  const float* Wk   = (const float*)d_in[4];
  const float* Wv   = (const float*)d_in[5];
  const float* Wo   = (const float*)d_in[6];
  const float* bo   = (const float*)d_in[7];
  float* out = (float*)d_out;
  char* ws = (char*)d_ws;

  const size_t MB = 1024 * 1024;
  u16*   xb      = (u16*)(ws);
  u16*   Wt      = (u16*)(ws + 16 * MB);
  float* qkv_lin = (float*)(ws + 28 * MB);
  u16*   Wot     = (u16*)(ws + 76 * MB);
  u16*   qb_buf  = (u16*)(ws);             // alias xb (dead after GEMM1)
  u16*   kb      = (u16*)(ws + 16 * MB);   // alias Wt
  u16*   vt      = (u16*)(ws + 20 * MB);   // alias Wt+4M
  u16*   y       = (u16*)(ws + 28 * MB);   // alias qkv_lin head

  // 1. x -> bf16
  convert_bf16<<<(MTOT * CC / 8 + 255) / 256, 256, 0, stream>>>(x, xb, MTOT * CC / 8);

  // 2. weight transposes -> bf16
  transpose_w<<<dim3(CC / 32, CC / 32), dim3(32, 8), 0, stream>>>(Wq, Wt, CC, 0);
  transpose_w<<<dim3(NKV * HD / 32, CC / 32), dim3(32, 8), 0, stream>>>(Wk, Wt, NKV * HD, CC);
  transpose_w<<<dim3(NKV * HD / 32, CC / 32), dim3(32, 8), 0, stream>>>(Wv, Wt, NKV * HD, CC + NKV * HD);
  transpose_w<<<dim3(CC / 32, CC / 32), dim3(32, 8), 0, stream>>>(Wo, Wot, CC, 0);

  // 3. fused QKV GEMM: (M=4096, N=3072, K=2048) fp32 out
  gemm_bt_bf16<<<dim3(NQKV / 128, MTOT / 128), 256, 0, stream>>>(
      xb, Wt, nullptr, qkv_lin, MTOT, NQKV, CC);

  // 4. RMSNorm + RoPE -> bf16 q/k head-major (wave per head)
  qkv_post<<<dim3(MTOT, 5), 256, 0, stream>>>(qkv_lin, cosp, sinp, qb_buf, kb);

  // 5. V -> (B,KV,D,T) bf16
  v_transpose<<<dim3(TT / 32, HD / 32, BB * NKV), dim3(32, 8), 0, stream>>>(qkv_lin, vt);

  // 6. MFMA flash attention v4 (unnormalized softmax) -> y bf16 (M x C)
  attn_mfma<<<dim3(16, BB * NH), 256, 0, stream>>>(qb_buf, kb, vt, y);

  // 7. out-proj GEMM + bias: (M=4096, N=2048, K=2048) fp32 out
  gemm_bt_bf16<<<dim3(CC / 128, MTOT / 128), 256, 0, stream>>>(
      y, Wot, bo, out, MTOT, CC, CC);
}

// Round 6
// 336.718 us; speedup vs baseline: 10.7315x; 1.0259x over previous
//
#include <hip/hip_runtime.h>
#include <hip/hip_bf16.h>
#include <math.h>

// Problem constants (B=2, T=2048, C=2048, NH=16, NKV=4, D=128, HALF=64)
#define BB 2
#define TT 2048
#define CC 2048
#define NH 16
#define NKV 4
#define HD 128
#define HALF 64
#define MTOT (BB*TT)            // 4096
#define NQKV (CC + 2*NKV*HD)    // 3072 (fused q|k|v columns)

typedef unsigned short u16;
typedef __attribute__((ext_vector_type(8))) short bf16x8;
typedef __attribute__((ext_vector_type(4))) float f32x4;

// fp32 -> bf16 (round-to-nearest-even)
__device__ __forceinline__ u16 f2bf(float f) {
  unsigned u = __float_as_uint(f);
  unsigned r = (u + 0x7FFFu + ((u >> 16) & 1u)) >> 16;
  return (u16)r;
}
__device__ __forceinline__ float bf2f(u16 v) {
  return __uint_as_float(((unsigned)v) << 16);
}

// async global->LDS, 16B per lane; lds base must be wave-uniform (HW adds lane*16)
__device__ __forceinline__ void gl_lds16(const void* g, void* l) {
  __builtin_amdgcn_global_load_lds(
      (const __attribute__((address_space(1))) unsigned int*)g,
      (__attribute__((address_space(3))) unsigned int*)l, 16, 0, 0);
}

// ---------------------------------------------------------------------------
// prep: fused x->bf16 convert (z=4) + 4 weight transposes (z=0..3).
// grid (64, 64, 5), block (32, 8).
//   z=0: Wq (N=2048) -> Wt rows 0..2047
//   z=1: Wk (N=512)  -> Wt rows 2048..2559
//   z=2: Wv (N=512)  -> Wt rows 2560..3071
//   z=3: Wo (N=2048) -> Wot
//   z=4: x fp32 -> xb bf16 (4096 blocks x 2048 elems)
// ---------------------------------------------------------------------------
__global__ __launch_bounds__(256) void prep(
    const float* __restrict__ x, const float* __restrict__ Wq,
    const float* __restrict__ Wk, const float* __restrict__ Wv,
    const float* __restrict__ Wo, u16* __restrict__ xb,
    u16* __restrict__ Wt, u16* __restrict__ Wot) {
  const int z = blockIdx.z;
  const int tx = threadIdx.x, ty = threadIdx.y;
  if (z == 4) {
    const int tid = ty * 32 + tx;
    const int i = (blockIdx.y * 64 + blockIdx.x) * 256 + tid;  // 8-elem group
    const float4* s4 = (const float4*)x;
    float4 a = s4[(size_t)i * 2], b = s4[(size_t)i * 2 + 1];
    bf16x8 o;
    o[0] = (short)f2bf(a.x); o[1] = (short)f2bf(a.y);
    o[2] = (short)f2bf(a.z); o[3] = (short)f2bf(a.w);
    o[4] = (short)f2bf(b.x); o[5] = (short)f2bf(b.y);
    o[6] = (short)f2bf(b.z); o[7] = (short)f2bf(b.w);
    ((bf16x8*)xb)[i] = o;
    return;
  }
  const float* W; u16* dst; int N; int row_off;
  if (z == 0)      { W = Wq; dst = Wt;  N = 2048; row_off = 0; }
  else if (z == 1) { W = Wk; dst = Wt;  N = 512;  row_off = 2048; }
  else if (z == 2) { W = Wv; dst = Wt;  N = 512;  row_off = 2560; }
  else             { W = Wo; dst = Wot; N = 2048; row_off = 0; }
  const int n0 = blockIdx.x * 32, k0 = blockIdx.y * 32;
  if (n0 >= N) return;
  __shared__ float tile[32][33];
#pragma unroll
  for (int i = 0; i < 4; ++i)
    tile[ty + 8 * i][tx] = W[(size_t)(k0 + ty + 8 * i) * N + n0 + tx];
  __syncthreads();
#pragma unroll
  for (int i = 0; i < 4; ++i)
    dst[(size_t)(row_off + n0 + ty + 8 * i) * CC + k0 + tx] =
        f2bf(tile[tx][ty + 8 * i]);
}

// ---------------------------------------------------------------------------
// bf16 MFMA GEMM (m97 structure). out_bf16: write u16 instead of fp32.
// ---------------------------------------------------------------------------
__global__ __launch_bounds__(256) void gemm_bt_bf16(
    const u16* __restrict__ A, const u16* __restrict__ Bt,
    const float* __restrict__ bias, float* __restrict__ C,
    int M, int N, int K, int out_bf16) {
  __shared__ u16 As[128 * 32];
  __shared__ u16 Bs[128 * 32];
  const int tid = threadIdx.x;
  const int wave = tid >> 6, lane = tid & 63;
  const int quad = lane >> 4, lo = lane & 15;
  const int bm = blockIdx.y * 128, bn = blockIdx.x * 128;
  const int wm = (wave & 1) * 64, wn = (wave >> 1) * 64;

  f32x4 acc[4][4];
#pragma unroll
  for (int i = 0; i < 4; ++i)
#pragma unroll
    for (int j = 0; j < 4; ++j)
#pragma unroll
      for (int r = 0; r < 4; ++r) acc[i][j][r] = 0.f;

  const int iss0 = wave * 2, iss1 = wave * 2 + 1;
  const int e0 = iss0 * 512 + lane * 8, e1 = iss1 * 512 + lane * 8;
  const int r0 = e0 >> 5, c0 = e0 & 31;
  const int r1 = e1 >> 5, c1 = e1 & 31;

  for (int k0 = 0; k0 < K; k0 += 32) {
    gl_lds16(A + (size_t)(bm + r0) * K + k0 + c0, (char*)As + iss0 * 1024);
    gl_lds16(A + (size_t)(bm + r1) * K + k0 + c1, (char*)As + iss1 * 1024);
    gl_lds16(Bt + (size_t)(bn + r0) * K + k0 + c0, (char*)Bs + iss0 * 1024);
    gl_lds16(Bt + (size_t)(bn + r1) * K + k0 + c1, (char*)Bs + iss1 * 1024);
    __syncthreads();

    bf16x8 af[4], bg[4];
#pragma unroll
    for (int i = 0; i < 4; ++i)
      af[i] = *(const bf16x8*)&As[(wm + i * 16 + lo) * 32 + quad * 8];
#pragma unroll
    for (int j = 0; j < 4; ++j)
      bg[j] = *(const bf16x8*)&Bs[(wn + j * 16 + lo) * 32 + quad * 8];
#pragma unroll
    for (int i = 0; i < 4; ++i)
#pragma unroll
      for (int j = 0; j < 4; ++j)
        acc[i][j] = __builtin_amdgcn_mfma_f32_16x16x32_bf16(af[i], bg[j], acc[i][j], 0, 0, 0);
    __syncthreads();
  }

#pragma unroll
  for (int i = 0; i < 4; ++i)
#pragma unroll
    for (int j = 0; j < 4; ++j)
#pragma unroll
      for (int r = 0; r < 4; ++r) {
        int row = bm + wm + i * 16 + quad * 4 + r;
        int col = bn + wn + j * 16 + lo;
        float v = acc[i][j][r];
        if (bias) v += bias[col];
        if (out_bf16) ((u16*)C)[(size_t)row * N + col] = f2bf(v);
        else          C[(size_t)row * N + col] = v;
      }
}

// ---------------------------------------------------------------------------
// RMSNorm + RoPE from bf16 qkv_lin, one wave per (b,t,head). grid (B*T, 5).
// ---------------------------------------------------------------------------
__global__ __launch_bounds__(256) void qkv_post(
    const u16* __restrict__ qkv_lin, const float* __restrict__ cosp,
    const float* __restrict__ sinp, u16* __restrict__ q, u16* __restrict__ k) {
  const int bt = blockIdx.x;
  const int hh = blockIdx.y * 4 + (threadIdx.x >> 6);   // 0..19
  const int lane = threadIdx.x & 63;
  const int t = bt & (TT - 1), b = bt >> 11;
  const int col = (hh < NH) ? hh * HD : CC + (hh - NH) * HD;
  const u16* src = qkv_lin + (size_t)bt * NQKV + col;
  float v1 = bf2f(src[lane]), v2 = bf2f(src[lane + 64]);
  float ss = v1 * v1 + v2 * v2;
#pragma unroll
  for (int mm = 1; mm < 64; mm <<= 1) ss += __shfl_xor(ss, mm, 64);
  float rms = rsqrtf(ss * (1.f / 128.f) + 1.1920929e-7f);
  float c = cosp[t * HALF + lane], s = sinp[t * HALF + lane];
  float o1 = v1 * rms * c - v2 * rms * s;
  float o2 = v1 * rms * s + v2 * rms * c;
  if (hh < NH) {
    u16* dst = q + (((size_t)(b * NH + hh)) * TT + t) * HD;
    dst[lane] = f2bf(o1); dst[lane + 64] = f2bf(o2);
  } else {
    u16* dst = k + (((size_t)(b * NKV + (hh - NH))) * TT + t) * HD;
    dst[lane] = f2bf(o1); dst[lane + 64] = f2bf(o2);
  }
}

// ---------------------------------------------------------------------------
// v part of qkv_lin (bf16) -> vt (B,KV,D,T) with kv PERMUTED within each
// 32-block: stored position p(kv) = ((kv>>2)&3)*8 + (kv&3) + 4*((kv>>4)&1).
// This makes the attention PV A-fragment a pure register repack (see attn).
// ---------------------------------------------------------------------------
__global__ __launch_bounds__(256) void v_transpose(
    const u16* __restrict__ qkv_lin, u16* __restrict__ vt) {
  __shared__ u16 tile[32][33];
  const int t0 = blockIdx.x * 32, d0 = blockIdx.y * 32;
  const int p = blockIdx.z;             // b*NKV + kv
  const int b = p >> 2, kv = p & 3;
  const int tx = threadIdx.x, ty = threadIdx.y;
#pragma unroll
  for (int i = 0; i < 4; ++i)
    tile[ty + 8 * i][tx] =
        qkv_lin[(size_t)(b * TT + t0 + ty + 8 * i) * NQKV + CC + NKV * HD + kv * HD + d0 + tx];
  __syncthreads();
  const int tperm = ((tx >> 2) & 3) * 8 + (tx & 3) + 4 * ((tx >> 4) & 1);
#pragma unroll
  for (int i = 0; i < 4; ++i)
    vt[((size_t)p * HD + d0 + ty + 8 * i) * TT + t0 + tperm] = tile[tx][ty + 8 * i];
}

// ---------------------------------------------------------------------------
// S^T softmax + A-fragment pack, all in registers.
// Lane (quad,lo) holds S^T C-layout: q-row = lo, kv = t0 + ct*16 + quad*4 + r.
// A-frag chunk k2 elem j  <->  own register (ct = k2*2+(j>>2), r = j&3)
// because V's kv order is permuted to kv' = k2*32 + 16*(j>>2) + quad*4 + (j&3).
// ---------------------------------------------------------------------------
__device__ __forceinline__ void softmax_pack(
    const f32x4* sacc, float& l_lane, bf16x8* ap, int rowq, int t0,
    bool diag, int quad) {
  const float cc = 0.12751744050808612f;   // log2(e)/sqrt(128)
  float e[4][4];
  if (diag) {
#pragma unroll
    for (int ct = 0; ct < 4; ++ct)
#pragma unroll
      for (int r = 0; r < 4; ++r) {
        float v = __builtin_amdgcn_exp2f(sacc[ct][r] * cc);
        if (t0 + ct * 16 + quad * 4 + r > rowq) v = 0.f;
        l_lane += v; e[ct][r] = v;
      }
  } else {
#pragma unroll
    for (int ct = 0; ct < 4; ++ct)
#pragma unroll
      for (int r = 0; r < 4; ++r) {
        float v = __builtin_amdgcn_exp2f(sacc[ct][r] * cc);
        l_lane += v; e[ct][r] = v;
      }
  }
#pragma unroll
  for (int k2 = 0; k2 < 2; ++k2) {
    bf16x8 ch;
#pragma unroll
    for (int j = 0; j < 8; ++j)
      ch[j] = (short)f2bf(e[k2 * 2 + (j >> 2)][j & 3]);
    ap[k2] = ch;
  }
}

// ---------------------------------------------------------------------------
// MFMA flash attention v5. grid (16, 32), block 256 (4 waves).
// Block owns q-tiles qt and 31-qt (complementary pairing, uniform MFMA work).
// S computed TRANSPOSED (K as A-operand, Q as B-operand) so the P transpose
// for PV is a pure register repack (V kv-order permuted by v_transpose).
// K and V both double-buffered (64 KB LDS, 2 blocks/CU); ONE barrier/pass.
// ---------------------------------------------------------------------------
__global__ __launch_bounds__(256, 2) void attn_mfma(
    const u16* __restrict__ Qb, const u16* __restrict__ Kb,
    const u16* __restrict__ Vt, u16* __restrict__ Y) {
  __shared__ u16 Ks[2][8192];   // 16 sets (ct*4+kc) x 512, dbuf
  __shared__ u16 Vs[2][8192];   // 16 sets (dt*2+k2) x 512, dbuf

  const int qt = blockIdx.x;    // pair (qt, 31-qt)
  const int bh = blockIdx.y;
  const int b = bh >> 4, h = bh & 15, kvh = h >> 2;
  const int tid = threadIdx.x;
  const int wave = tid >> 6, lane = tid & 63;
  const int quad = lane >> 4, lo = lane & 15;

  const int rowsA = qt * 64, rowsB = (31 - qt) * 64;
  const u16* Qg = Qb + (size_t)(b * NH + h) * TT * HD;
  const u16* Kg = Kb + (size_t)(b * NKV + kvh) * TT * HD;
  const u16* Vg = Vt + (size_t)(b * NKV + kvh) * HD * TT;

  // Q fragments, used as MFMA B-operand (n=lo -> q-row, k=quad*8+j)
  bf16x8 aq[2][4];
#pragma unroll
  for (int kc = 0; kc < 4; ++kc) {
    aq[0][kc] = *(const bf16x8*)(Qg + (size_t)(rowsA + wave * 16 + lo) * HD + kc * 32 + quad * 8);
    aq[1][kc] = *(const bf16x8*)(Qg + (size_t)(rowsB + wave * 16 + lo) * HD + kc * 32 + quad * 8);
  }

  // staging: wave stages sets wave*4..wave*4+3 for K and V
  const u16* kgp[4]; const u16* vgp[4];
  u16* klp[2][4]; u16* vlp[2][4];
#pragma unroll
  for (int c = 0; c < 4; ++c) {
    const int s = wave * 4 + c;
    const int ct = s >> 2, kq = s & 3;
    kgp[c] = Kg + (size_t)(ct * 16 + lo) * HD + kq * 32 + quad * 8;
    const int dt = s >> 1, k2 = s & 1;
    vgp[c] = Vg + (size_t)(dt * 16 + lo) * TT + k2 * 32 + quad * 8;
    klp[0][c] = &Ks[0][s * 512]; klp[1][c] = &Ks[1][s * 512];
    vlp[0][c] = &Vs[0][s * 512]; vlp[1][c] = &Vs[1][s * 512];
  }

  f32x4 oacc[2][8];
#pragma unroll
  for (int rb = 0; rb < 2; ++rb)
#pragma unroll
    for (int dt = 0; dt < 8; ++dt)
#pragma unroll
      for (int r = 0; r < 4; ++r) oacc[rb][dt][r] = 0.f;
  float l_lane[2] = {0.f, 0.f};

  const int ntiles = 32 - qt;
  const int rowqA = rowsA + wave * 16 + lo;   // this lane's q-row (tile A)
  const int rowqB = rowsB + wave * 16 + lo;

  // prologue: stage tile 0 -> buf 0
#pragma unroll
  for (int c = 0; c < 4; ++c) {
    gl_lds16(kgp[c], klp[0][c]); kgp[c] += 64 * HD;
    gl_lds16(vgp[c], vlp[0][c]); vgp[c] += 64;
  }

  for (int nt = 0; nt < ntiles; ++nt) {
    const int par = nt & 1;
    __syncthreads();  // tile nt landed (vmcnt drained); buf[par^1] readers done
    if (nt + 1 < ntiles) {
#pragma unroll
      for (int c = 0; c < 4; ++c) {
        gl_lds16(kgp[c], klp[par ^ 1][c]); kgp[c] += 64 * HD;
        gl_lds16(vgp[c], vlp[par ^ 1][c]); vgp[c] += 64;
      }
    }
    const u16* ksb = Ks[par];
    const u16* vsb = Vs[par];
    const int t0 = nt * 64;
    const bool act0 = (nt <= qt);

    // S^T = K Q^T: D row (quad*4+r) = kv, col (lo) = q-row
    f32x4 sacc[2][4];
#pragma unroll
    for (int rb = 0; rb < 2; ++rb)
#pragma unroll
      for (int ct = 0; ct < 4; ++ct)
#pragma unroll
        for (int r = 0; r < 4; ++r) sacc[rb][ct][r] = 0.f;
#pragma unroll
    for (int ct = 0; ct < 4; ++ct)
#pragma unroll
      for (int kc = 0; kc < 4; ++kc) {
        bf16x8 bk = *(const bf16x8*)&ksb[(ct * 4 + kc) * 512 + lane * 8];
        sacc[1][ct] = __builtin_amdgcn_mfma_f32_16x16x32_bf16(bk, aq[1][kc], sacc[1][ct], 0, 0, 0);
        if (act0)
          sacc[0][ct] = __builtin_amdgcn_mfma_f32_16x16x32_bf16(bk, aq[0][kc], sacc[0][ct], 0, 0, 0);
      }

    // softmax + register P pack
    bf16x8 ap[2][2];
    softmax_pack(sacc[1], l_lane[1], ap[1], rowqB, t0,
                 t0 + 63 > rowsB + wave * 16, quad);
    if (act0)
      softmax_pack(sacc[0], l_lane[0], ap[0], rowqA, t0,
                   t0 + 63 > rowsA + wave * 16, quad);

    // O += P @ V  (V already in permuted kv order matching the pack)
#pragma unroll
    for (int dt = 0; dt < 8; ++dt)
#pragma unroll
      for (int k2 = 0; k2 < 2; ++k2) {
        bf16x8 bv = *(const bf16x8*)&vsb[(dt * 2 + k2) * 512 + lane * 8];
        oacc[1][dt] = __builtin_amdgcn_mfma_f32_16x16x32_bf16(ap[1][k2], bv, oacc[1][dt], 0, 0, 0);
        if (act0)
          oacc[0][dt] = __builtin_amdgcn_mfma_f32_16x16x32_bf16(ap[0][k2], bv, oacc[0][dt], 0, 0, 0);
      }
  }

  // epilogue: l for q-row `lo` -> reduce over quad lanes; fetch per-output-row
  float linv[2][4];
#pragma unroll
  for (int rb = 0; rb < 2; ++rb) {
    float l = l_lane[rb];
    l += __shfl_xor(l, 16, 64);
    l += __shfl_xor(l, 32, 64);
    l = 1.f / l;                       // valid at lane lo for row lo (all quads)
#pragma unroll
    for (int r = 0; r < 4; ++r)
      linv[rb][r] = __shfl(l, quad * 4 + r, 64);   // row quad*4+r lives at lane quad*4+r
  }
#pragma unroll
  for (int rb = 0; rb < 2; ++rb) {
    const int rows = (rb == 0) ? rowsA : rowsB;
    const size_t row0 = (size_t)b * TT + rows + wave * 16 + quad * 4;
#pragma unroll
    for (int dt = 0; dt < 8; ++dt)
#pragma unroll
      for (int r = 0; r < 4; ++r)
        Y[(row0 + r) * CC + h * HD + dt * 16 + lo] = f2bf(oacc[rb][dt][r] * linv[rb][r]);
  }
}

// ---------------------------------------------------------------------------
// kernel_launch. ws layout (bytes):
//   [0,16M):   xb (bf16 x)            -> later qb_buf (bf16 q, B,H,T,D)
//   [16M,28M): Wt (bf16 qkv^T)        -> later kb (4M) + vt (8M)
//   [28M,52M): qkv_lin bf16 (M x 3072)-> first 16M later y (bf16, M x C)
//   [52M,60M): Wot (bf16 Wo^T)
// ---------------------------------------------------------------------------
extern "C" void kernel_launch(void* const* d_in, const int* in_sizes, int n_in,
                              void* d_out, int out_size, void* d_ws, size_t ws_size,
                              hipStream_t stream) {
  (void)in_sizes; (void)n_in; (void)out_size; (void)ws_size;
  const float* x    = (const float*)d_in[0];
  const float* cosp = (const float*)d_in[1];
  const float* sinp = (const float*)d_in[2];
  const float* Wq   = (const float*)d_in[3];
  const float* Wk   = (const float*)d_in[4];
  const float* Wv   = (const float*)d_in[5];
  const float* Wo   = (const float*)d_in[6];
  const float* bo   = (const float*)d_in[7];
  float* out = (float*)d_out;
  char* ws = (char*)d_ws;

  const size_t MB = 1024 * 1024;
  u16* xb      = (u16*)(ws);
  u16* Wt      = (u16*)(ws + 16 * MB);
  u16* qkv_lin = (u16*)(ws + 28 * MB);
  u16* Wot     = (u16*)(ws + 52 * MB);
  u16* qb_buf  = (u16*)(ws);             // alias xb (dead after GEMM1)
  u16* kb      = (u16*)(ws + 16 * MB);   // alias Wt
  u16* vt      = (u16*)(ws + 20 * MB);   // alias Wt+4M
  u16* y       = (u16*)(ws + 28 * MB);   // alias qkv_lin head (dead after post)

  // 1. fused convert + weight transposes
  prep<<<dim3(64, 64, 5), dim3(32, 8), 0, stream>>>(x, Wq, Wk, Wv, Wo, xb, Wt, Wot);

  // 2. fused QKV GEMM (M=4096, N=3072, K=2048), bf16 out
  gemm_bt_bf16<<<dim3(NQKV / 128, MTOT / 128), 256, 0, stream>>>(
      xb, Wt, nullptr, (float*)qkv_lin, MTOT, NQKV, CC, 1);

  // 3. RMSNorm + RoPE -> bf16 q/k head-major
  qkv_post<<<dim3(MTOT, 5), 256, 0, stream>>>(qkv_lin, cosp, sinp, qb_buf, kb);

  // 4. V -> (B,KV,D,T) bf16, kv-permuted
  v_transpose<<<dim3(TT / 32, HD / 32, BB * NKV), dim3(32, 8), 0, stream>>>(qkv_lin, vt);

  // 5. MFMA flash attention v5 -> y bf16 (M x C)
  attn_mfma<<<dim3(16, BB * NH), 256, 0, stream>>>(qb_buf, kb, vt, y);

  // 6. out-proj GEMM + bias (fp32 out)
  gemm_bt_bf16<<<dim3(CC / 128, MTOT / 128), 256, 0, stream>>>(
      y, Wot, bo, out, MTOT, CC, CC, 0);
}